// Round 4
// baseline (2416.275 us; speedup 1.0000x reference)
//
#include <hip/hip_runtime.h>

#define THREADS 256
#define LVLS 16
#define TSZ 524288u
#define TMASK 524287u
#define PRIME1 2654435761u
#define HID 64
#define ENC_WORDS 96   // per point: 6 planes * 16 levels, one uint (2 bf16) each

constexpr float resf(int l) { double r = 16.0; for (int i = 0; i < l; ++i) r *= 1.3819; return (float)r; }

__device__ __constant__ float c_RES[LVLS] = {
    resf(0),  resf(1),  resf(2),  resf(3),
    resf(4),  resf(5),  resf(6),  resf(7),
    resf(8),  resf(9),  resf(10), resf(11),
    resf(12), resf(13), resf(14), resf(15)
};

__device__ __forceinline__ unsigned packbf2(float a, float b) {
    unsigned ua = __float_as_uint(a), ub = __float_as_uint(b);
    ua += 0x7FFFu + ((ua >> 16) & 1u);   // RNE to bf16
    ub += 0x7FFFu + ((ub >> 16) & 1u);
    return (ua >> 16) | (ub & 0xFFFF0000u);
}

// ---------------- Kernel 1: hash-grid gather -> bf16 enc in workspace ----------------
// thread = (plane s, point p); writes 64 B (16 levels * 2 bf16).
__global__ __launch_bounds__(THREADS, 6) void hashgrid_k(
    const float* __restrict__ pxy, const float* __restrict__ pxz,
    const float* __restrict__ pyz, const float* __restrict__ pxt,
    const float* __restrict__ pyt, const float* __restrict__ pzt,
    const float* __restrict__ tables, unsigned* __restrict__ enc, int npts)
{
    const int gid = blockIdx.x * THREADS + threadIdx.x;
    if (gid >= 6 * npts) return;
    const int s = gid / npts;          // wave-uniform (npts % 256 == 0)
    const int p = gid - s * npts;

    float2 pt;
    switch (s) {
        case 0: pt = ((const float2*)pxy)[p]; break;
        case 1: pt = ((const float2*)pxz)[p]; break;
        case 2: pt = ((const float2*)pyz)[p]; break;
        case 3: pt = ((const float2*)pxt)[p]; break;
        case 4: pt = ((const float2*)pyt)[p]; break;
        default: pt = ((const float2*)pzt)[p]; break;
    }
    const float4* tab4 = (const float4*)tables + (size_t)s * LVLS * (TSZ / 2);

    unsigned ew[LVLS];
    #pragma unroll
    for (int l = 0; l < LVLS; ++l) {
        const float r = c_RES[l];
        const float fx = pt.x * r, fy = pt.y * r;
        const float flx = floorf(fx), fly = floorf(fy);
        const float wx = fx - flx, wy = fy - fly;
        const unsigned x0 = (unsigned)(int)flx;
        const unsigned y0 = (unsigned)(int)fly;
        const unsigned hy0 = y0 * PRIME1;
        const unsigned hy1 = hy0 + PRIME1;
        // corner hashes; x-neighbors share an aligned float4 pair when x0 even
        const unsigned qa = (x0 ^ hy0) & TMASK;
        const unsigned qb = ((x0 + 1u) ^ hy0) & TMASK;
        const unsigned qc = (x0 ^ hy1) & TMASK;
        const unsigned qd = ((x0 + 1u) ^ hy1) & TMASK;
        const float4* t4 = tab4 + (size_t)l * (TSZ / 2);
        const float4 A = t4[qa >> 1];
        const float4 B = t4[qb >> 1];
        const float4 C = t4[qc >> 1];
        const float4 D = t4[qd >> 1];
        const float f00x = (qa & 1) ? A.z : A.x, f00y = (qa & 1) ? A.w : A.y;
        const float f10x = (qb & 1) ? B.z : B.x, f10y = (qb & 1) ? B.w : B.y;
        const float f01x = (qc & 1) ? C.z : C.x, f01y = (qc & 1) ? C.w : C.y;
        const float f11x = (qd & 1) ? D.z : D.x, f11y = (qd & 1) ? D.w : D.y;

        const float w00 = (1.f - wx) * (1.f - wy);
        const float w10 = wx * (1.f - wy);
        const float w01 = (1.f - wx) * wy;
        const float w11 = wx * wy;
        const float e0 = f00x * w00 + f10x * w10 + f01x * w01 + f11x * w11;
        const float e1 = f00y * w00 + f10y * w10 + f01y * w01 + f11y * w11;
        ew[l] = packbf2(e0, e1);
    }

    uint4* dst = (uint4*)(enc + (size_t)p * ENC_WORDS + s * LVLS);
    dst[0] = make_uint4(ew[0],  ew[1],  ew[2],  ew[3]);
    dst[1] = make_uint4(ew[4],  ew[5],  ew[6],  ew[7]);
    dst[2] = make_uint4(ew[8],  ew[9],  ew[10], ew[11]);
    dst[3] = make_uint4(ew[12], ew[13], ew[14], ew[15]);
}

// ---------------- Kernel 2: MLP from enc + raw coords ----------------
#define PROC(u, c) { \
    const float elo = __uint_as_float((u) << 16); \
    const float ehi = __uint_as_float((u) & 0xFFFF0000u); \
    const float4* wa = (const float4*)(wbase + (2*(c)) * HID); \
    const float4* wb = wa + 16; \
    _Pragma("unroll") \
    for (int qq = 0; qq < 16; ++qq) { \
        const float4 a = wa[qq]; const float4 b = wb[qq]; \
        h1[4*qq+0] += elo * a.x + ehi * b.x; \
        h1[4*qq+1] += elo * a.y + ehi * b.y; \
        h1[4*qq+2] += elo * a.z + ehi * b.z; \
        h1[4*qq+3] += elo * a.w + ehi * b.w; } }

__global__ __launch_bounds__(THREADS, 4) void mlp_k(
    const float* __restrict__ pxy, const float* __restrict__ pxz,
    const float* __restrict__ pyz, const float* __restrict__ pxt,
    const float* __restrict__ pyt, const float* __restrict__ pzt,
    const unsigned* __restrict__ enc, const float* __restrict__ W1,
    const float* __restrict__ W2, const float* __restrict__ W3,
    float* __restrict__ out, int npts)
{
    const int gid = blockIdx.x * THREADS + threadIdx.x;
    if (gid >= npts) return;

    float h1[HID];
    #pragma unroll
    for (int k = 0; k < HID; ++k) h1[k] = 0.f;

    const uint4* erow = (const uint4*)(enc + (size_t)gid * ENC_WORDS);

    #pragma unroll 1
    for (int s = 0; s < 6; ++s) {
        const float* w1s = W1 + (s * 34) * HID;
        #pragma unroll 1
        for (int j = 0; j < 4; ++j) {
            const uint4 q = erow[s * 4 + j];
            const float* wbase = w1s + (j * 8) * HID;
            PROC(q.x, 0)
            PROC(q.y, 1)
            PROC(q.z, 2)
            PROC(q.w, 3)
        }
        float2 pt;
        switch (s) {
            case 0: pt = ((const float2*)pxy)[gid]; break;
            case 1: pt = ((const float2*)pxz)[gid]; break;
            case 2: pt = ((const float2*)pyz)[gid]; break;
            case 3: pt = ((const float2*)pxt)[gid]; break;
            case 4: pt = ((const float2*)pyt)[gid]; break;
            default: pt = ((const float2*)pzt)[gid]; break;
        }
        const float4* wa = (const float4*)(w1s + 32 * HID);
        const float4* wb = wa + 16;
        #pragma unroll
        for (int qq = 0; qq < 16; ++qq) {
            const float4 a = wa[qq];
            const float4 b = wb[qq];
            h1[4*qq+0] += pt.x * a.x + pt.y * b.x;
            h1[4*qq+1] += pt.x * a.y + pt.y * b.y;
            h1[4*qq+2] += pt.x * a.z + pt.y * b.z;
            h1[4*qq+3] += pt.x * a.w + pt.y * b.w;
        }
    }

    #pragma unroll
    for (int k = 0; k < HID; ++k) h1[k] = fmaxf(h1[k], 0.f);

    float o0 = 0.f, o1 = 0.f, o2 = 0.f;
    #pragma unroll 1
    for (int c = 0; c < 4; ++c) {
        float t[16];
        #pragma unroll
        for (int i = 0; i < 16; ++i) t[i] = 0.f;
        #pragma unroll
        for (int k = 0; k < HID; ++k) {
            const float4* w2r = (const float4*)(W2 + k * HID + c * 16);
            const float hk = h1[k];
            const float4 a = w2r[0];
            const float4 b = w2r[1];
            const float4 d = w2r[2];
            const float4 e = w2r[3];
            t[0]  += hk * a.x;  t[1]  += hk * a.y;  t[2]  += hk * a.z;  t[3]  += hk * a.w;
            t[4]  += hk * b.x;  t[5]  += hk * b.y;  t[6]  += hk * b.z;  t[7]  += hk * b.w;
            t[8]  += hk * d.x;  t[9]  += hk * d.y;  t[10] += hk * d.z;  t[11] += hk * d.w;
            t[12] += hk * e.x;  t[13] += hk * e.y;  t[14] += hk * e.z;  t[15] += hk * e.w;
        }
        #pragma unroll
        for (int i = 0; i < 16; ++i) {
            const float tt = fmaxf(t[i], 0.f);
            const int m = c * 16 + i;
            o0 += tt * W3[m * 3 + 0];
            o1 += tt * W3[m * 3 + 1];
            o2 += tt * W3[m * 3 + 2];
        }
    }

    out[3 * gid + 0] = o0;
    out[3 * gid + 1] = o1;
    out[3 * gid + 2] = o2;
}

// ---------------- Fallback: R3 fused kernel (used only if ws too small) ----------------
__global__ __launch_bounds__(THREADS, 4) void fused_mono(
    const float* __restrict__ pxy, const float* __restrict__ pxz,
    const float* __restrict__ pyz, const float* __restrict__ pxt,
    const float* __restrict__ pyt, const float* __restrict__ pzt,
    const float* __restrict__ tables, const float* __restrict__ W1,
    const float* __restrict__ W2, const float* __restrict__ W3,
    float* __restrict__ out, int npts)
{
    const int gid = blockIdx.x * THREADS + threadIdx.x;

    float h1[HID];
    #pragma unroll
    for (int k = 0; k < HID; ++k) h1[k] = 0.f;

    #pragma unroll 1
    for (int s = 0; s < 6; ++s) {
        float2 pt;
        switch (s) {
            case 0: pt = ((const float2*)pxy)[gid]; break;
            case 1: pt = ((const float2*)pxz)[gid]; break;
            case 2: pt = ((const float2*)pyz)[gid]; break;
            case 3: pt = ((const float2*)pxt)[gid]; break;
            case 4: pt = ((const float2*)pyt)[gid]; break;
            default: pt = ((const float2*)pzt)[gid]; break;
        }
        const float px = pt.x, py = pt.y;
        const float2* tbase = ((const float2*)tables) + (size_t)s * LVLS * TSZ;
        const float* w1s = W1 + (s * 34) * HID;

        #pragma unroll 2
        for (int l = 0; l < LVLS; ++l) {
            const float r = c_RES[l];
            const float fx = px * r, fy = py * r;
            const float flx = floorf(fx), fly = floorf(fy);
            const float wx = fx - flx, wy = fy - fly;
            const unsigned x0 = (unsigned)(int)flx;
            const unsigned y0 = (unsigned)(int)fly;
            const unsigned hy0 = y0 * PRIME1;
            const unsigned hy1 = hy0 + PRIME1;
            const float2* tab = tbase + (size_t)l * TSZ;
            const float2 f00 = tab[(x0 ^ hy0) & TMASK];
            const float2 f10 = tab[((x0 + 1u) ^ hy0) & TMASK];
            const float2 f01 = tab[(x0 ^ hy1) & TMASK];
            const float2 f11 = tab[((x0 + 1u) ^ hy1) & TMASK];
            const float w00 = (1.f - wx) * (1.f - wy);
            const float w10 = wx * (1.f - wy);
            const float w01 = (1.f - wx) * wy;
            const float w11 = wx * wy;
            const float e0 = f00.x * w00 + f10.x * w10 + f01.x * w01 + f11.x * w11;
            const float e1 = f00.y * w00 + f10.y * w10 + f01.y * w01 + f11.y * w11;
            const float4* wa = (const float4*)(w1s + (2 * l) * HID);
            const float4* wb = wa + 16;
            #pragma unroll
            for (int q = 0; q < 16; ++q) {
                const float4 a = wa[q];
                const float4 b = wb[q];
                h1[4*q+0] += e0 * a.x + e1 * b.x;
                h1[4*q+1] += e0 * a.y + e1 * b.y;
                h1[4*q+2] += e0 * a.z + e1 * b.z;
                h1[4*q+3] += e0 * a.w + e1 * b.w;
            }
        }
        const float4* wa = (const float4*)(w1s + 32 * HID);
        const float4* wb = wa + 16;
        #pragma unroll
        for (int q = 0; q < 16; ++q) {
            const float4 a = wa[q];
            const float4 b = wb[q];
            h1[4*q+0] += px * a.x + py * b.x;
            h1[4*q+1] += px * a.y + py * b.y;
            h1[4*q+2] += px * a.z + py * b.z;
            h1[4*q+3] += px * a.w + py * b.w;
        }
    }

    #pragma unroll
    for (int k = 0; k < HID; ++k) h1[k] = fmaxf(h1[k], 0.f);

    float o0 = 0.f, o1 = 0.f, o2 = 0.f;
    #pragma unroll 1
    for (int c = 0; c < 4; ++c) {
        float t[16];
        #pragma unroll
        for (int i = 0; i < 16; ++i) t[i] = 0.f;
        #pragma unroll
        for (int k = 0; k < HID; ++k) {
            const float4* w2r = (const float4*)(W2 + k * HID + c * 16);
            const float hk = h1[k];
            const float4 a = w2r[0];
            const float4 b = w2r[1];
            const float4 d = w2r[2];
            const float4 e = w2r[3];
            t[0]  += hk * a.x;  t[1]  += hk * a.y;  t[2]  += hk * a.z;  t[3]  += hk * a.w;
            t[4]  += hk * b.x;  t[5]  += hk * b.y;  t[6]  += hk * b.z;  t[7]  += hk * b.w;
            t[8]  += hk * d.x;  t[9]  += hk * d.y;  t[10] += hk * d.z;  t[11] += hk * d.w;
            t[12] += hk * e.x;  t[13] += hk * e.y;  t[14] += hk * e.z;  t[15] += hk * e.w;
        }
        #pragma unroll
        for (int i = 0; i < 16; ++i) {
            const float tt = fmaxf(t[i], 0.f);
            const int m = c * 16 + i;
            o0 += tt * W3[m * 3 + 0];
            o1 += tt * W3[m * 3 + 1];
            o2 += tt * W3[m * 3 + 2];
        }
    }

    if (gid < npts) {
        out[3 * gid + 0] = o0;
        out[3 * gid + 1] = o1;
        out[3 * gid + 2] = o2;
    }
}

extern "C" void kernel_launch(void* const* d_in, const int* in_sizes, int n_in,
                              void* d_out, int out_size, void* d_ws, size_t ws_size,
                              hipStream_t stream)
{
    const float* pxy = (const float*)d_in[0];
    const float* pxz = (const float*)d_in[1];
    const float* pyz = (const float*)d_in[2];
    const float* pxt = (const float*)d_in[3];
    const float* pyt = (const float*)d_in[4];
    const float* pzt = (const float*)d_in[5];
    const float* tables = (const float*)d_in[6];
    const float* W1 = (const float*)d_in[7];
    const float* W2 = (const float*)d_in[8];
    const float* W3 = (const float*)d_in[9];
    float* out = (float*)d_out;

    const int npts = in_sizes[0] / 2;
    const size_t enc_bytes = (size_t)npts * ENC_WORDS * 4;

    if (ws_size >= enc_bytes) {
        unsigned* enc = (unsigned*)d_ws;
        const int g1 = (6 * npts + THREADS - 1) / THREADS;
        hipLaunchKernelGGL(hashgrid_k, dim3(g1), dim3(THREADS), 0, stream,
                           pxy, pxz, pyz, pxt, pyt, pzt, tables, enc, npts);
        const int g2 = (npts + THREADS - 1) / THREADS;
        hipLaunchKernelGGL(mlp_k, dim3(g2), dim3(THREADS), 0, stream,
                           pxy, pxz, pyz, pxt, pyt, pzt, enc, W1, W2, W3, out, npts);
    } else {
        const int g = (npts + THREADS - 1) / THREADS;
        hipLaunchKernelGGL(fused_mono, dim3(g), dim3(THREADS), 0, stream,
                           pxy, pxz, pyz, pxt, pyt, pzt, tables, W1, W2, W3, out, npts);
    }
}

// Round 5
// 1925.159 us; speedup vs baseline: 1.2551x; 1.2551x over previous
//
#include <hip/hip_runtime.h>

#define THREADS 256
#define LVLS 16
#define TSZ 524288u
#define TMASK 524287u
#define PRIME1 2654435761u
#define HID 64
#define NBIN 4096          // 64x64 Morton bins per plane
#define ENC_WORDS 96       // per point: 6 planes * 16 levels, one uint (2xbf16) each

constexpr float resf(int l) { double r = 16.0; for (int i = 0; i < l; ++i) r *= 1.3819; return (float)r; }

__device__ __constant__ float c_RES[LVLS] = {
    resf(0),  resf(1),  resf(2),  resf(3),
    resf(4),  resf(5),  resf(6),  resf(7),
    resf(8),  resf(9),  resf(10), resf(11),
    resf(12), resf(13), resf(14), resf(15)
};

__device__ __forceinline__ unsigned packbf2(float a, float b) {
    unsigned ua = __float_as_uint(a), ub = __float_as_uint(b);
    ua += 0x7FFFu + ((ua >> 16) & 1u);   // RNE to bf16
    ub += 0x7FFFu + ((ub >> 16) & 1u);
    return (ua >> 16) | (ub & 0xFFFF0000u);
}

__device__ __forceinline__ unsigned part1by1(unsigned v) {
    v &= 0xFFu;
    v = (v | (v << 4)) & 0x0F0Fu;
    v = (v | (v << 2)) & 0x3333u;
    v = (v | (v << 1)) & 0x5555u;
    return v;
}

__device__ __forceinline__ float2 load_pt(int s, int i,
    const float* pxy, const float* pxz, const float* pyz,
    const float* pxt, const float* pyt, const float* pzt)
{
    switch (s) {
        case 0: return ((const float2*)pxy)[i];
        case 1: return ((const float2*)pxz)[i];
        case 2: return ((const float2*)pyz)[i];
        case 3: return ((const float2*)pxt)[i];
        case 4: return ((const float2*)pyt)[i];
        default: return ((const float2*)pzt)[i];
    }
}

__device__ __forceinline__ unsigned bin_key(float2 pt) {
    const int xb = min(63, (int)(pt.x * 64.f));
    const int yb = min(63, (int)(pt.y * 64.f));
    return part1by1((unsigned)xb) | (part1by1((unsigned)yb) << 1);
}

// ---------------- sort pipeline ----------------
__global__ void zero_hist_k(int* __restrict__ hist) {
    const int i = blockIdx.x * blockDim.x + threadIdx.x;
    if (i < 6 * NBIN) hist[i] = 0;
}

__global__ __launch_bounds__(THREADS) void hist_k(
    const float* __restrict__ pxy, const float* __restrict__ pxz,
    const float* __restrict__ pyz, const float* __restrict__ pxt,
    const float* __restrict__ pyt, const float* __restrict__ pzt,
    int* __restrict__ hist, int npts, int bpp)
{
    const int s = blockIdx.x / bpp;
    const int i = (blockIdx.x - s * bpp) * THREADS + threadIdx.x;
    if (i >= npts) return;
    const float2 pt = load_pt(s, i, pxy, pxz, pyz, pxt, pyt, pzt);
    atomicAdd(&hist[s * NBIN + bin_key(pt)], 1);
}

__global__ __launch_bounds__(1024) void scan_k(
    const int* __restrict__ hist, int* __restrict__ curs)
{
    __shared__ int sb[1024];
    const int p = blockIdx.x;
    const int t = threadIdx.x;
    const int h0 = hist[p * NBIN + 4 * t + 0];
    const int h1 = hist[p * NBIN + 4 * t + 1];
    const int h2 = hist[p * NBIN + 4 * t + 2];
    const int h3 = hist[p * NBIN + 4 * t + 3];
    const int i1 = h0 + h1;
    const int i2 = i1 + h2;
    const int i3 = i2 + h3;
    sb[t] = i3;
    __syncthreads();
    for (int off = 1; off < 1024; off <<= 1) {
        const int v = (t >= off) ? sb[t - off] : 0;
        __syncthreads();
        sb[t] += v;
        __syncthreads();
    }
    const int start = sb[t] - i3;   // exclusive within plane
    curs[p * NBIN + 4 * t + 0] = start;
    curs[p * NBIN + 4 * t + 1] = start + h0;
    curs[p * NBIN + 4 * t + 2] = start + i1;
    curs[p * NBIN + 4 * t + 3] = start + i2;
}

__global__ __launch_bounds__(THREADS) void scatter_k(
    const float* __restrict__ pxy, const float* __restrict__ pxz,
    const float* __restrict__ pyz, const float* __restrict__ pxt,
    const float* __restrict__ pyt, const float* __restrict__ pzt,
    int* __restrict__ curs, float2* __restrict__ sxy, int* __restrict__ sidx,
    int npts, int bpp)
{
    const int s = blockIdx.x / bpp;
    const int i = (blockIdx.x - s * bpp) * THREADS + threadIdx.x;
    if (i >= npts) return;
    const float2 pt = load_pt(s, i, pxy, pxz, pyz, pxt, pyt, pzt);
    const int pos = atomicAdd(&curs[s * NBIN + bin_key(pt)], 1);
    sxy[(size_t)s * npts + pos] = pt;
    sidx[(size_t)s * npts + pos] = i;
}

// ---------------- sorted hash-grid gather ----------------
__global__ __launch_bounds__(THREADS, 6) void gather_sorted_k(
    const float* __restrict__ tables, const float2* __restrict__ sxy,
    const int* __restrict__ sidx, unsigned* __restrict__ enc,
    int npts, int bpp)
{
    const int s = blockIdx.x / bpp;
    const int i = (blockIdx.x - s * bpp) * THREADS + threadIdx.x;
    if (i >= npts) return;

    const float2 pt = sxy[(size_t)s * npts + i];
    const int orig = sidx[(size_t)s * npts + i];
    const float2* tbase = ((const float2*)tables) + (size_t)s * LVLS * TSZ;

    unsigned ew[LVLS];
    #pragma unroll
    for (int l = 0; l < LVLS; ++l) {
        const float r = c_RES[l];
        const float fx = pt.x * r, fy = pt.y * r;
        const float flx = floorf(fx), fly = floorf(fy);
        const float wx = fx - flx, wy = fy - fly;
        const unsigned x0 = (unsigned)(int)flx;
        const unsigned y0 = (unsigned)(int)fly;
        const unsigned hy0 = y0 * PRIME1;
        const unsigned hy1 = hy0 + PRIME1;
        const float2* tab = tbase + (size_t)l * TSZ;
        const float2 f00 = tab[(x0 ^ hy0) & TMASK];
        const float2 f10 = tab[((x0 + 1u) ^ hy0) & TMASK];
        const float2 f01 = tab[(x0 ^ hy1) & TMASK];
        const float2 f11 = tab[((x0 + 1u) ^ hy1) & TMASK];
        const float w00 = (1.f - wx) * (1.f - wy);
        const float w10 = wx * (1.f - wy);
        const float w01 = (1.f - wx) * wy;
        const float w11 = wx * wy;
        const float e0 = f00.x * w00 + f10.x * w10 + f01.x * w01 + f11.x * w11;
        const float e1 = f00.y * w00 + f10.y * w10 + f01.y * w01 + f11.y * w11;
        ew[l] = packbf2(e0, e1);
    }

    uint4* dst = (uint4*)(enc + (size_t)orig * ENC_WORDS + s * LVLS);
    dst[0] = make_uint4(ew[0],  ew[1],  ew[2],  ew[3]);
    dst[1] = make_uint4(ew[4],  ew[5],  ew[6],  ew[7]);
    dst[2] = make_uint4(ew[8],  ew[9],  ew[10], ew[11]);
    dst[3] = make_uint4(ew[12], ew[13], ew[14], ew[15]);
}

// ---------------- MLP (unchanged from R4) ----------------
#define PROC(u, c) { \
    const float elo = __uint_as_float((u) << 16); \
    const float ehi = __uint_as_float((u) & 0xFFFF0000u); \
    const float4* wa = (const float4*)(wbase + (2*(c)) * HID); \
    const float4* wb = wa + 16; \
    _Pragma("unroll") \
    for (int qq = 0; qq < 16; ++qq) { \
        const float4 a = wa[qq]; const float4 b = wb[qq]; \
        h1[4*qq+0] += elo * a.x + ehi * b.x; \
        h1[4*qq+1] += elo * a.y + ehi * b.y; \
        h1[4*qq+2] += elo * a.z + ehi * b.z; \
        h1[4*qq+3] += elo * a.w + ehi * b.w; } }

__global__ __launch_bounds__(THREADS, 4) void mlp_k(
    const float* __restrict__ pxy, const float* __restrict__ pxz,
    const float* __restrict__ pyz, const float* __restrict__ pxt,
    const float* __restrict__ pyt, const float* __restrict__ pzt,
    const unsigned* __restrict__ enc, const float* __restrict__ W1,
    const float* __restrict__ W2, const float* __restrict__ W3,
    float* __restrict__ out, int npts)
{
    const int gid = blockIdx.x * THREADS + threadIdx.x;
    if (gid >= npts) return;

    float h1[HID];
    #pragma unroll
    for (int k = 0; k < HID; ++k) h1[k] = 0.f;

    const uint4* erow = (const uint4*)(enc + (size_t)gid * ENC_WORDS);

    #pragma unroll 1
    for (int s = 0; s < 6; ++s) {
        const float* w1s = W1 + (s * 34) * HID;
        #pragma unroll 1
        for (int j = 0; j < 4; ++j) {
            const uint4 q = erow[s * 4 + j];
            const float* wbase = w1s + (j * 8) * HID;
            PROC(q.x, 0)
            PROC(q.y, 1)
            PROC(q.z, 2)
            PROC(q.w, 3)
        }
        const float2 pt = load_pt(s, gid, pxy, pxz, pyz, pxt, pyt, pzt);
        const float4* wa = (const float4*)(w1s + 32 * HID);
        const float4* wb = wa + 16;
        #pragma unroll
        for (int qq = 0; qq < 16; ++qq) {
            const float4 a = wa[qq];
            const float4 b = wb[qq];
            h1[4*qq+0] += pt.x * a.x + pt.y * b.x;
            h1[4*qq+1] += pt.x * a.y + pt.y * b.y;
            h1[4*qq+2] += pt.x * a.z + pt.y * b.z;
            h1[4*qq+3] += pt.x * a.w + pt.y * b.w;
        }
    }

    #pragma unroll
    for (int k = 0; k < HID; ++k) h1[k] = fmaxf(h1[k], 0.f);

    float o0 = 0.f, o1 = 0.f, o2 = 0.f;
    #pragma unroll 1
    for (int c = 0; c < 4; ++c) {
        float t[16];
        #pragma unroll
        for (int i = 0; i < 16; ++i) t[i] = 0.f;
        #pragma unroll
        for (int k = 0; k < HID; ++k) {
            const float4* w2r = (const float4*)(W2 + k * HID + c * 16);
            const float hk = h1[k];
            const float4 a = w2r[0];
            const float4 b = w2r[1];
            const float4 d = w2r[2];
            const float4 e = w2r[3];
            t[0]  += hk * a.x;  t[1]  += hk * a.y;  t[2]  += hk * a.z;  t[3]  += hk * a.w;
            t[4]  += hk * b.x;  t[5]  += hk * b.y;  t[6]  += hk * b.z;  t[7]  += hk * b.w;
            t[8]  += hk * d.x;  t[9]  += hk * d.y;  t[10] += hk * d.z;  t[11] += hk * d.w;
            t[12] += hk * e.x;  t[13] += hk * e.y;  t[14] += hk * e.z;  t[15] += hk * e.w;
        }
        #pragma unroll
        for (int i = 0; i < 16; ++i) {
            const float tt = fmaxf(t[i], 0.f);
            const int m = c * 16 + i;
            o0 += tt * W3[m * 3 + 0];
            o1 += tt * W3[m * 3 + 1];
            o2 += tt * W3[m * 3 + 2];
        }
    }

    out[3 * gid + 0] = o0;
    out[3 * gid + 1] = o1;
    out[3 * gid + 2] = o2;
}

// ---------------- Fallback: R3 fused kernel ----------------
__global__ __launch_bounds__(THREADS, 4) void fused_mono(
    const float* __restrict__ pxy, const float* __restrict__ pxz,
    const float* __restrict__ pyz, const float* __restrict__ pxt,
    const float* __restrict__ pyt, const float* __restrict__ pzt,
    const float* __restrict__ tables, const float* __restrict__ W1,
    const float* __restrict__ W2, const float* __restrict__ W3,
    float* __restrict__ out, int npts)
{
    const int gid = blockIdx.x * THREADS + threadIdx.x;

    float h1[HID];
    #pragma unroll
    for (int k = 0; k < HID; ++k) h1[k] = 0.f;

    #pragma unroll 1
    for (int s = 0; s < 6; ++s) {
        const float2 pt = load_pt(s, gid, pxy, pxz, pyz, pxt, pyt, pzt);
        const float px = pt.x, py = pt.y;
        const float2* tbase = ((const float2*)tables) + (size_t)s * LVLS * TSZ;
        const float* w1s = W1 + (s * 34) * HID;

        #pragma unroll 2
        for (int l = 0; l < LVLS; ++l) {
            const float r = c_RES[l];
            const float fx = px * r, fy = py * r;
            const float flx = floorf(fx), fly = floorf(fy);
            const float wx = fx - flx, wy = fy - fly;
            const unsigned x0 = (unsigned)(int)flx;
            const unsigned y0 = (unsigned)(int)fly;
            const unsigned hy0 = y0 * PRIME1;
            const unsigned hy1 = hy0 + PRIME1;
            const float2* tab = tbase + (size_t)l * TSZ;
            const float2 f00 = tab[(x0 ^ hy0) & TMASK];
            const float2 f10 = tab[((x0 + 1u) ^ hy0) & TMASK];
            const float2 f01 = tab[(x0 ^ hy1) & TMASK];
            const float2 f11 = tab[((x0 + 1u) ^ hy1) & TMASK];
            const float w00 = (1.f - wx) * (1.f - wy);
            const float w10 = wx * (1.f - wy);
            const float w01 = (1.f - wx) * wy;
            const float w11 = wx * wy;
            const float e0 = f00.x * w00 + f10.x * w10 + f01.x * w01 + f11.x * w11;
            const float e1 = f00.y * w00 + f10.y * w10 + f01.y * w01 + f11.y * w11;
            const float4* wa = (const float4*)(w1s + (2 * l) * HID);
            const float4* wb = wa + 16;
            #pragma unroll
            for (int q = 0; q < 16; ++q) {
                const float4 a = wa[q];
                const float4 b = wb[q];
                h1[4*q+0] += e0 * a.x + e1 * b.x;
                h1[4*q+1] += e0 * a.y + e1 * b.y;
                h1[4*q+2] += e0 * a.z + e1 * b.z;
                h1[4*q+3] += e0 * a.w + e1 * b.w;
            }
        }
        const float4* wa = (const float4*)(w1s + 32 * HID);
        const float4* wb = wa + 16;
        #pragma unroll
        for (int q = 0; q < 16; ++q) {
            const float4 a = wa[q];
            const float4 b = wb[q];
            h1[4*q+0] += px * a.x + py * b.x;
            h1[4*q+1] += px * a.y + py * b.y;
            h1[4*q+2] += px * a.z + py * b.z;
            h1[4*q+3] += px * a.w + py * b.w;
        }
    }

    #pragma unroll
    for (int k = 0; k < HID; ++k) h1[k] = fmaxf(h1[k], 0.f);

    float o0 = 0.f, o1 = 0.f, o2 = 0.f;
    #pragma unroll 1
    for (int c = 0; c < 4; ++c) {
        float t[16];
        #pragma unroll
        for (int i = 0; i < 16; ++i) t[i] = 0.f;
        #pragma unroll
        for (int k = 0; k < HID; ++k) {
            const float4* w2r = (const float4*)(W2 + k * HID + c * 16);
            const float hk = h1[k];
            const float4 a = w2r[0];
            const float4 b = w2r[1];
            const float4 d = w2r[2];
            const float4 e = w2r[3];
            t[0]  += hk * a.x;  t[1]  += hk * a.y;  t[2]  += hk * a.z;  t[3]  += hk * a.w;
            t[4]  += hk * b.x;  t[5]  += hk * b.y;  t[6]  += hk * b.z;  t[7]  += hk * b.w;
            t[8]  += hk * d.x;  t[9]  += hk * d.y;  t[10] += hk * d.z;  t[11] += hk * d.w;
            t[12] += hk * e.x;  t[13] += hk * e.y;  t[14] += hk * e.z;  t[15] += hk * e.w;
        }
        #pragma unroll
        for (int i = 0; i < 16; ++i) {
            const float tt = fmaxf(t[i], 0.f);
            const int m = c * 16 + i;
            o0 += tt * W3[m * 3 + 0];
            o1 += tt * W3[m * 3 + 1];
            o2 += tt * W3[m * 3 + 2];
        }
    }

    if (gid < npts) {
        out[3 * gid + 0] = o0;
        out[3 * gid + 1] = o1;
        out[3 * gid + 2] = o2;
    }
}

extern "C" void kernel_launch(void* const* d_in, const int* in_sizes, int n_in,
                              void* d_out, int out_size, void* d_ws, size_t ws_size,
                              hipStream_t stream)
{
    const float* pxy = (const float*)d_in[0];
    const float* pxz = (const float*)d_in[1];
    const float* pyz = (const float*)d_in[2];
    const float* pxt = (const float*)d_in[3];
    const float* pyt = (const float*)d_in[4];
    const float* pzt = (const float*)d_in[5];
    const float* tables = (const float*)d_in[6];
    const float* W1 = (const float*)d_in[7];
    const float* W2 = (const float*)d_in[8];
    const float* W3 = (const float*)d_in[9];
    float* out = (float*)d_out;

    const int npts = in_sizes[0] / 2;
    const int bpp = (npts + THREADS - 1) / THREADS;

    // workspace layout
    const size_t off_hist = 0;
    const size_t off_curs = off_hist + (size_t)6 * NBIN * 4;
    const size_t off_sxy  = 256 * 1024;                      // 256 KB aligned
    const size_t off_sidx = off_sxy + (size_t)6 * npts * 8;
    size_t off_enc = off_sidx + (size_t)6 * npts * 4;
    off_enc = (off_enc + 127) & ~(size_t)127;
    const size_t need = off_enc + (size_t)npts * ENC_WORDS * 4;

    if (ws_size >= need) {
        char* ws = (char*)d_ws;
        int* hist = (int*)(ws + off_hist);
        int* curs = (int*)(ws + off_curs);
        float2* sxy = (float2*)(ws + off_sxy);
        int* sidx = (int*)(ws + off_sidx);
        unsigned* enc = (unsigned*)(ws + off_enc);

        hipLaunchKernelGGL(zero_hist_k, dim3((6 * NBIN + THREADS - 1) / THREADS),
                           dim3(THREADS), 0, stream, hist);
        hipLaunchKernelGGL(hist_k, dim3(6 * bpp), dim3(THREADS), 0, stream,
                           pxy, pxz, pyz, pxt, pyt, pzt, hist, npts, bpp);
        hipLaunchKernelGGL(scan_k, dim3(6), dim3(1024), 0, stream, hist, curs);
        hipLaunchKernelGGL(scatter_k, dim3(6 * bpp), dim3(THREADS), 0, stream,
                           pxy, pxz, pyz, pxt, pyt, pzt, curs, sxy, sidx, npts, bpp);
        hipLaunchKernelGGL(gather_sorted_k, dim3(6 * bpp), dim3(THREADS), 0, stream,
                           tables, sxy, sidx, enc, npts, bpp);
        hipLaunchKernelGGL(mlp_k, dim3(bpp), dim3(THREADS), 0, stream,
                           pxy, pxz, pyz, pxt, pyt, pzt, enc, W1, W2, W3, out, npts);
    } else {
        hipLaunchKernelGGL(fused_mono, dim3(bpp), dim3(THREADS), 0, stream,
                           pxy, pxz, pyz, pxt, pyt, pzt, tables, W1, W2, W3, out, npts);
    }
}

// Round 6
// 1481.502 us; speedup vs baseline: 1.6310x; 1.2995x over previous
//
#include <hip/hip_runtime.h>

#define THREADS 256
#define LVLS 16
#define TSZ 524288u
#define TMASK 524287u
#define PRIME1 2654435761u
#define HID 64
#define NBIN 4096          // 64x64 Morton bins per plane
#define ENC_STRIDE 104     // uint words per point: 96 hash + 6 coord + 2 pad (208 bf16)
#define MLP_TILES 8

typedef __attribute__((ext_vector_type(8))) short bf16x8;
typedef __attribute__((ext_vector_type(4))) float f32x4;

constexpr float resf(int l) { double r = 16.0; for (int i = 0; i < l; ++i) r *= 1.3819; return (float)r; }

__device__ __constant__ float c_RES[LVLS] = {
    resf(0),  resf(1),  resf(2),  resf(3),
    resf(4),  resf(5),  resf(6),  resf(7),
    resf(8),  resf(9),  resf(10), resf(11),
    resf(12), resf(13), resf(14), resf(15)
};

__device__ __forceinline__ unsigned packbf2(float a, float b) {
    unsigned ua = __float_as_uint(a), ub = __float_as_uint(b);
    ua += 0x7FFFu + ((ua >> 16) & 1u);   // RNE to bf16
    ub += 0x7FFFu + ((ub >> 16) & 1u);
    return (ua >> 16) | (ub & 0xFFFF0000u);
}

__device__ __forceinline__ unsigned short bf16rne(float f) {
    unsigned u = __float_as_uint(f);
    u += 0x7FFFu + ((u >> 16) & 1u);
    return (unsigned short)(u >> 16);
}

__device__ __forceinline__ unsigned part1by1(unsigned v) {
    v &= 0xFFu;
    v = (v | (v << 4)) & 0x0F0Fu;
    v = (v | (v << 2)) & 0x3333u;
    v = (v | (v << 1)) & 0x5555u;
    return v;
}

__device__ __forceinline__ float2 load_pt(int s, int i,
    const float* pxy, const float* pxz, const float* pyz,
    const float* pxt, const float* pyt, const float* pzt)
{
    switch (s) {
        case 0: return ((const float2*)pxy)[i];
        case 1: return ((const float2*)pxz)[i];
        case 2: return ((const float2*)pyz)[i];
        case 3: return ((const float2*)pxt)[i];
        case 4: return ((const float2*)pyt)[i];
        default: return ((const float2*)pzt)[i];
    }
}

__device__ __forceinline__ unsigned bin_key(float2 pt) {
    const int xb = min(63, (int)(pt.x * 64.f));
    const int yb = min(63, (int)(pt.y * 64.f));
    return part1by1((unsigned)xb) | (part1by1((unsigned)yb) << 1);
}

// ---------------- weight prep: pack W1/W2 into bf16 MFMA B-fragment order ----------------
// B-frag slot e = ((t*4 + n)*64 + lane)*8 + j ; k = t*32 + (lane>>4)*8 + j ; col = n*16 + (lane&15)
// k mapping: k<192: plane s=k/32, rem=k%32 -> W1 row s*34+rem ; 192<=k<204: coords -> row s*34+32+c ; else 0
__global__ __launch_bounds__(256) void pack_w1_k(const float* __restrict__ W1,
                                                 unsigned short* __restrict__ W1B)
{
    const int e = blockIdx.x * 256 + threadIdx.x;
    if (e >= 7 * 4 * 64 * 8) return;
    const int j = e & 7;
    const int lane = (e >> 3) & 63;
    const int n = (e >> 9) & 3;
    const int t = e >> 11;
    const int k = t * 32 + ((lane >> 4) << 3) + j;
    const int col = n * 16 + (lane & 15);
    float v = 0.f;
    if (k < 192) { const int s = k >> 5, rem = k & 31; v = W1[(s * 34 + rem) * HID + col]; }
    else if (k < 204) { const int q = k - 192; v = W1[((q >> 1) * 34 + 32 + (q & 1)) * HID + col]; }
    W1B[e] = bf16rne(v);
}

__global__ __launch_bounds__(256) void pack_w2_k(const float* __restrict__ W2,
                                                 unsigned short* __restrict__ W2B)
{
    const int e = blockIdx.x * 256 + threadIdx.x;
    if (e >= 2 * 4 * 64 * 8) return;
    const int j = e & 7;
    const int lane = (e >> 3) & 63;
    const int n = (e >> 9) & 3;
    const int t = e >> 11;
    const int k = t * 32 + ((lane >> 4) << 3) + j;
    const int col = n * 16 + (lane & 15);
    W2B[e] = bf16rne(W2[k * HID + col]);
}

// ---------------- sort pipeline ----------------
__global__ void zero_hist_k(int* __restrict__ hist) {
    const int i = blockIdx.x * blockDim.x + threadIdx.x;
    if (i < 6 * NBIN) hist[i] = 0;
}

__global__ __launch_bounds__(THREADS) void hist_k(
    const float* __restrict__ pxy, const float* __restrict__ pxz,
    const float* __restrict__ pyz, const float* __restrict__ pxt,
    const float* __restrict__ pyt, const float* __restrict__ pzt,
    int* __restrict__ hist, int npts, int bpp)
{
    const int s = blockIdx.x / bpp;
    const int i = (blockIdx.x - s * bpp) * THREADS + threadIdx.x;
    if (i >= npts) return;
    const float2 pt = load_pt(s, i, pxy, pxz, pyz, pxt, pyt, pzt);
    atomicAdd(&hist[s * NBIN + bin_key(pt)], 1);
}

__global__ __launch_bounds__(1024) void scan_k(
    const int* __restrict__ hist, int* __restrict__ curs)
{
    __shared__ int sb[1024];
    const int p = blockIdx.x;
    const int t = threadIdx.x;
    const int h0 = hist[p * NBIN + 4 * t + 0];
    const int h1 = hist[p * NBIN + 4 * t + 1];
    const int h2 = hist[p * NBIN + 4 * t + 2];
    const int h3 = hist[p * NBIN + 4 * t + 3];
    const int i1 = h0 + h1;
    const int i2 = i1 + h2;
    const int i3 = i2 + h3;
    sb[t] = i3;
    __syncthreads();
    for (int off = 1; off < 1024; off <<= 1) {
        const int v = (t >= off) ? sb[t - off] : 0;
        __syncthreads();
        sb[t] += v;
        __syncthreads();
    }
    const int start = sb[t] - i3;   // exclusive within plane
    curs[p * NBIN + 4 * t + 0] = start;
    curs[p * NBIN + 4 * t + 1] = start + h0;
    curs[p * NBIN + 4 * t + 2] = start + i1;
    curs[p * NBIN + 4 * t + 3] = start + i2;
}

__global__ __launch_bounds__(THREADS) void scatter_k(
    const float* __restrict__ pxy, const float* __restrict__ pxz,
    const float* __restrict__ pyz, const float* __restrict__ pxt,
    const float* __restrict__ pyt, const float* __restrict__ pzt,
    int* __restrict__ curs, int* __restrict__ sidx, int npts, int bpp)
{
    const int s = blockIdx.x / bpp;
    const int i = (blockIdx.x - s * bpp) * THREADS + threadIdx.x;
    if (i >= npts) return;
    const float2 pt = load_pt(s, i, pxy, pxz, pyz, pxt, pyt, pzt);
    const int pos = atomicAdd(&curs[s * NBIN + bin_key(pt)], 1);
    sidx[(size_t)s * npts + pos] = i;
}

// ---------------- sorted hash-grid gather -> bf16 enc (stride 104 words) ----------------
__global__ __launch_bounds__(THREADS, 6) void gather_sorted_k(
    const float* __restrict__ pxy, const float* __restrict__ pxz,
    const float* __restrict__ pyz, const float* __restrict__ pxt,
    const float* __restrict__ pyt, const float* __restrict__ pzt,
    const float* __restrict__ tables, const int* __restrict__ sidx,
    unsigned* __restrict__ encW, int npts, int bpp)
{
    const int s = blockIdx.x / bpp;
    const int i = (blockIdx.x - s * bpp) * THREADS + threadIdx.x;
    if (i >= npts) return;

    const int orig = sidx[(size_t)s * npts + i];
    const float2 pt = load_pt(s, orig, pxy, pxz, pyz, pxt, pyt, pzt);
    const float2* tbase = ((const float2*)tables) + (size_t)s * LVLS * TSZ;

    unsigned ew[LVLS];
    #pragma unroll
    for (int l = 0; l < LVLS; ++l) {
        const float r = c_RES[l];
        const float fx = pt.x * r, fy = pt.y * r;
        const float flx = floorf(fx), fly = floorf(fy);
        const float wx = fx - flx, wy = fy - fly;
        const unsigned x0 = (unsigned)(int)flx;
        const unsigned y0 = (unsigned)(int)fly;
        const unsigned hy0 = y0 * PRIME1;
        const unsigned hy1 = hy0 + PRIME1;
        const float2* tab = tbase + (size_t)l * TSZ;
        const float2 f00 = tab[(x0 ^ hy0) & TMASK];
        const float2 f10 = tab[((x0 + 1u) ^ hy0) & TMASK];
        const float2 f01 = tab[(x0 ^ hy1) & TMASK];
        const float2 f11 = tab[((x0 + 1u) ^ hy1) & TMASK];
        const float w00 = (1.f - wx) * (1.f - wy);
        const float w10 = wx * (1.f - wy);
        const float w01 = (1.f - wx) * wy;
        const float w11 = wx * wy;
        const float e0 = f00.x * w00 + f10.x * w10 + f01.x * w01 + f11.x * w11;
        const float e1 = f00.y * w00 + f10.y * w10 + f01.y * w01 + f11.y * w11;
        ew[l] = packbf2(e0, e1);
    }

    unsigned* rowp = encW + (size_t)orig * ENC_STRIDE;
    uint4* dst = (uint4*)(rowp + s * LVLS);
    dst[0] = make_uint4(ew[0],  ew[1],  ew[2],  ew[3]);
    dst[1] = make_uint4(ew[4],  ew[5],  ew[6],  ew[7]);
    dst[2] = make_uint4(ew[8],  ew[9],  ew[10], ew[11]);
    dst[3] = make_uint4(ew[12], ew[13], ew[14], ew[15]);
    rowp[96 + s] = packbf2(pt.x, pt.y);          // coord features k=192+2s,193+2s
    if (s == 0) { rowp[102] = 0u; rowp[103] = 0u; }  // pad k=204..207
}

// ---------------- MFMA MLP ----------------
// wave = 16 points. Layer1: A = enc rows (global, K=224 w/ zero-padded B), B = packed W1 (LDS).
// h1 relu'd -> bf16 -> swizzled LDS -> Layer2 MFMA -> W3 dot + shfl reduce.
__global__ __launch_bounds__(256, 2) void mlp_mfma_k(
    const unsigned* __restrict__ encW, const unsigned short* __restrict__ W1Bg,
    const unsigned short* __restrict__ W2Bg, const float* __restrict__ W3,
    float* __restrict__ out, int npts)
{
    __shared__ uint4 sW1B[1792];          // 7 ksteps * 4 ntiles * 64 lanes * 16B
    __shared__ uint4 sW2B[512];
    __shared__ float sW3[192];
    __shared__ unsigned short sH1[4][1024];  // per-wave 16x64 bf16, XOR-swizzled

    const int tid = threadIdx.x;
    for (int i = tid; i < 1792; i += 256) sW1B[i] = ((const uint4*)W1Bg)[i];
    for (int i = tid; i < 512; i += 256) sW2B[i] = ((const uint4*)W2Bg)[i];
    for (int i = tid; i < 192; i += 256) sW3[i] = W3[i];
    __syncthreads();

    const int w = tid >> 6, lane = tid & 63;
    const int row = lane & 15, g = lane >> 4;
    const int blk0 = blockIdx.x * (64 * MLP_TILES);

    for (int it = 0; it < MLP_TILES; ++it) {
        const int p0 = blk0 + (it * 4 + w) * 16;
        if (p0 + 16 > npts) { __syncthreads(); __syncthreads(); continue; }

        f32x4 acc0 = {0.f,0.f,0.f,0.f}, acc1 = acc0, acc2_ = acc0, acc3 = acc0;
        const unsigned* arow = encW + (size_t)(p0 + row) * ENC_STRIDE;
        #pragma unroll
        for (int t = 0; t < 7; ++t) {
            const int gw = (t == 6) ? (g & 1) : g;   // last kstep: valid words only; B=0 beyond k=207
            const uint4 av = *(const uint4*)(arow + t * 16 + gw * 4);
            const bf16x8 a = *(const bf16x8*)&av;
            acc0 = __builtin_amdgcn_mfma_f32_16x16x32_bf16(a, *(const bf16x8*)&sW1B[(t*4+0)*64 + lane], acc0, 0, 0, 0);
            acc1 = __builtin_amdgcn_mfma_f32_16x16x32_bf16(a, *(const bf16x8*)&sW1B[(t*4+1)*64 + lane], acc1, 0, 0, 0);
            acc2_ = __builtin_amdgcn_mfma_f32_16x16x32_bf16(a, *(const bf16x8*)&sW1B[(t*4+2)*64 + lane], acc2_, 0, 0, 0);
            acc3 = __builtin_amdgcn_mfma_f32_16x16x32_bf16(a, *(const bf16x8*)&sW1B[(t*4+3)*64 + lane], acc3, 0, 0, 0);
        }

        // D layout: col = lane&15 (within 16-wide tile), row(point) = g*4 + reg
        #pragma unroll
        for (int r = 0; r < 4; ++r) {
            const int rr = g * 4 + r;
            const int base = rr * 64;
            const int swz = (rr & 7) << 3;
            sH1[w][(base + 0 * 16 + row) ^ swz] = bf16rne(fmaxf(acc0[r], 0.f));
            sH1[w][(base + 1 * 16 + row) ^ swz] = bf16rne(fmaxf(acc1[r], 0.f));
            sH1[w][(base + 2 * 16 + row) ^ swz] = bf16rne(fmaxf(acc2_[r], 0.f));
            sH1[w][(base + 3 * 16 + row) ^ swz] = bf16rne(fmaxf(acc3[r], 0.f));
        }
        __syncthreads();

        f32x4 b0 = {0.f,0.f,0.f,0.f}, b1 = b0, b2 = b0, b3 = b0;
        #pragma unroll
        for (int t = 0; t < 2; ++t) {
            const int kidx = (row * 64 + t * 32 + g * 8) ^ ((row & 7) << 3);
            const bf16x8 a2 = *(const bf16x8*)&sH1[w][kidx];
            b0 = __builtin_amdgcn_mfma_f32_16x16x32_bf16(a2, *(const bf16x8*)&sW2B[(t*4+0)*64 + lane], b0, 0, 0, 0);
            b1 = __builtin_amdgcn_mfma_f32_16x16x32_bf16(a2, *(const bf16x8*)&sW2B[(t*4+1)*64 + lane], b1, 0, 0, 0);
            b2 = __builtin_amdgcn_mfma_f32_16x16x32_bf16(a2, *(const bf16x8*)&sW2B[(t*4+2)*64 + lane], b2, 0, 0, 0);
            b3 = __builtin_amdgcn_mfma_f32_16x16x32_bf16(a2, *(const bf16x8*)&sW2B[(t*4+3)*64 + lane], b3, 0, 0, 0);
        }

        float o[4][3];
        #pragma unroll
        for (int r = 0; r < 4; ++r) { o[r][0] = 0.f; o[r][1] = 0.f; o[r][2] = 0.f; }
        #pragma unroll
        for (int n = 0; n < 4; ++n) {
            const int m = n * 16 + row;
            const float w30 = sW3[m * 3 + 0], w31 = sW3[m * 3 + 1], w32 = sW3[m * 3 + 2];
            const f32x4 bb = (n == 0) ? b0 : (n == 1) ? b1 : (n == 2) ? b2 : b3;
            #pragma unroll
            for (int r = 0; r < 4; ++r) {
                const float h = fmaxf(bb[r], 0.f);
                o[r][0] += h * w30; o[r][1] += h * w31; o[r][2] += h * w32;
            }
        }
        #pragma unroll
        for (int m = 1; m < 16; m <<= 1) {
            #pragma unroll
            for (int r = 0; r < 4; ++r) {
                o[r][0] += __shfl_xor(o[r][0], m, 64);
                o[r][1] += __shfl_xor(o[r][1], m, 64);
                o[r][2] += __shfl_xor(o[r][2], m, 64);
            }
        }
        if (row == 0) {
            #pragma unroll
            for (int r = 0; r < 4; ++r) {
                const int p = p0 + g * 4 + r;
                out[p * 3 + 0] = o[r][0];
                out[p * 3 + 1] = o[r][1];
                out[p * 3 + 2] = o[r][2];
            }
        }
        __syncthreads();   // WAR: reads done before next iter overwrites sH1
    }
}

// ---------------- Fallback: fused fp32 kernel (used only if ws too small) ----------------
__global__ __launch_bounds__(THREADS, 4) void fused_mono(
    const float* __restrict__ pxy, const float* __restrict__ pxz,
    const float* __restrict__ pyz, const float* __restrict__ pxt,
    const float* __restrict__ pyt, const float* __restrict__ pzt,
    const float* __restrict__ tables, const float* __restrict__ W1,
    const float* __restrict__ W2, const float* __restrict__ W3,
    float* __restrict__ out, int npts)
{
    const int gid = blockIdx.x * THREADS + threadIdx.x;

    float h1[HID];
    #pragma unroll
    for (int k = 0; k < HID; ++k) h1[k] = 0.f;

    #pragma unroll 1
    for (int s = 0; s < 6; ++s) {
        const float2 pt = load_pt(s, gid, pxy, pxz, pyz, pxt, pyt, pzt);
        const float px = pt.x, py = pt.y;
        const float2* tbase = ((const float2*)tables) + (size_t)s * LVLS * TSZ;
        const float* w1s = W1 + (s * 34) * HID;

        #pragma unroll 2
        for (int l = 0; l < LVLS; ++l) {
            const float r = c_RES[l];
            const float fx = px * r, fy = py * r;
            const float flx = floorf(fx), fly = floorf(fy);
            const float wx = fx - flx, wy = fy - fly;
            const unsigned x0 = (unsigned)(int)flx;
            const unsigned y0 = (unsigned)(int)fly;
            const unsigned hy0 = y0 * PRIME1;
            const unsigned hy1 = hy0 + PRIME1;
            const float2* tab = tbase + (size_t)l * TSZ;
            const float2 f00 = tab[(x0 ^ hy0) & TMASK];
            const float2 f10 = tab[((x0 + 1u) ^ hy0) & TMASK];
            const float2 f01 = tab[(x0 ^ hy1) & TMASK];
            const float2 f11 = tab[((x0 + 1u) ^ hy1) & TMASK];
            const float w00 = (1.f - wx) * (1.f - wy);
            const float w10 = wx * (1.f - wy);
            const float w01 = (1.f - wx) * wy;
            const float w11 = wx * wy;
            const float e0 = f00.x * w00 + f10.x * w10 + f01.x * w01 + f11.x * w11;
            const float e1 = f00.y * w00 + f10.y * w10 + f01.y * w01 + f11.y * w11;
            const float4* wa = (const float4*)(w1s + (2 * l) * HID);
            const float4* wb = wa + 16;
            #pragma unroll
            for (int q = 0; q < 16; ++q) {
                const float4 a = wa[q];
                const float4 b = wb[q];
                h1[4*q+0] += e0 * a.x + e1 * b.x;
                h1[4*q+1] += e0 * a.y + e1 * b.y;
                h1[4*q+2] += e0 * a.z + e1 * b.z;
                h1[4*q+3] += e0 * a.w + e1 * b.w;
            }
        }
        const float4* wa = (const float4*)(w1s + 32 * HID);
        const float4* wb = wa + 16;
        #pragma unroll
        for (int q = 0; q < 16; ++q) {
            const float4 a = wa[q];
            const float4 b = wb[q];
            h1[4*q+0] += px * a.x + py * b.x;
            h1[4*q+1] += px * a.y + py * b.y;
            h1[4*q+2] += px * a.z + py * b.z;
            h1[4*q+3] += px * a.w + py * b.w;
        }
    }

    #pragma unroll
    for (int k = 0; k < HID; ++k) h1[k] = fmaxf(h1[k], 0.f);

    float o0 = 0.f, o1 = 0.f, o2 = 0.f;
    #pragma unroll 1
    for (int c = 0; c < 4; ++c) {
        float t[16];
        #pragma unroll
        for (int i = 0; i < 16; ++i) t[i] = 0.f;
        #pragma unroll
        for (int k = 0; k < HID; ++k) {
            const float4* w2r = (const float4*)(W2 + k * HID + c * 16);
            const float hk = h1[k];
            const float4 a = w2r[0];
            const float4 b = w2r[1];
            const float4 d = w2r[2];
            const float4 e = w2r[3];
            t[0]  += hk * a.x;  t[1]  += hk * a.y;  t[2]  += hk * a.z;  t[3]  += hk * a.w;
            t[4]  += hk * b.x;  t[5]  += hk * b.y;  t[6]  += hk * b.z;  t[7]  += hk * b.w;
            t[8]  += hk * d.x;  t[9]  += hk * d.y;  t[10] += hk * d.z;  t[11] += hk * d.w;
            t[12] += hk * e.x;  t[13] += hk * e.y;  t[14] += hk * e.z;  t[15] += hk * e.w;
        }
        #pragma unroll
        for (int i = 0; i < 16; ++i) {
            const float tt = fmaxf(t[i], 0.f);
            const int m = c * 16 + i;
            o0 += tt * W3[m * 3 + 0];
            o1 += tt * W3[m * 3 + 1];
            o2 += tt * W3[m * 3 + 2];
        }
    }

    if (gid < npts) {
        out[3 * gid + 0] = o0;
        out[3 * gid + 1] = o1;
        out[3 * gid + 2] = o2;
    }
}

extern "C" void kernel_launch(void* const* d_in, const int* in_sizes, int n_in,
                              void* d_out, int out_size, void* d_ws, size_t ws_size,
                              hipStream_t stream)
{
    const float* pxy = (const float*)d_in[0];
    const float* pxz = (const float*)d_in[1];
    const float* pyz = (const float*)d_in[2];
    const float* pxt = (const float*)d_in[3];
    const float* pyt = (const float*)d_in[4];
    const float* pzt = (const float*)d_in[5];
    const float* tables = (const float*)d_in[6];
    const float* W1 = (const float*)d_in[7];
    const float* W2 = (const float*)d_in[8];
    const float* W3 = (const float*)d_in[9];
    float* out = (float*)d_out;

    const int npts = in_sizes[0] / 2;
    const int bpp = (npts + THREADS - 1) / THREADS;

    // workspace layout
    const size_t off_hist = 0;                               // 6*4096*4 = 96 KB
    const size_t off_curs = off_hist + (size_t)6 * NBIN * 4; // 96 KB
    const size_t off_w1b  = off_curs + (size_t)6 * NBIN * 4; // 28672 B
    const size_t off_w2b  = off_w1b + 28672;                 // 8192 B
    const size_t off_sidx = 256 * 1024;
    size_t off_enc = off_sidx + (size_t)6 * npts * 4;
    off_enc = (off_enc + 127) & ~(size_t)127;
    const size_t need = off_enc + (size_t)npts * ENC_STRIDE * 4;

    if (ws_size >= need && (npts % (64 * MLP_TILES)) == 0) {
        char* ws = (char*)d_ws;
        int* hist = (int*)(ws + off_hist);
        int* curs = (int*)(ws + off_curs);
        unsigned short* W1B = (unsigned short*)(ws + off_w1b);
        unsigned short* W2B = (unsigned short*)(ws + off_w2b);
        int* sidx = (int*)(ws + off_sidx);
        unsigned* encW = (unsigned*)(ws + off_enc);

        hipLaunchKernelGGL(zero_hist_k, dim3((6 * NBIN + THREADS - 1) / THREADS),
                           dim3(THREADS), 0, stream, hist);
        hipLaunchKernelGGL(hist_k, dim3(6 * bpp), dim3(THREADS), 0, stream,
                           pxy, pxz, pyz, pxt, pyt, pzt, hist, npts, bpp);
        hipLaunchKernelGGL(scan_k, dim3(6), dim3(1024), 0, stream, hist, curs);
        hipLaunchKernelGGL(pack_w1_k, dim3(56), dim3(256), 0, stream, W1, W1B);
        hipLaunchKernelGGL(pack_w2_k, dim3(16), dim3(256), 0, stream, W2, W2B);
        hipLaunchKernelGGL(scatter_k, dim3(6 * bpp), dim3(THREADS), 0, stream,
                           pxy, pxz, pyz, pxt, pyt, pzt, curs, sidx, npts, bpp);
        hipLaunchKernelGGL(gather_sorted_k, dim3(6 * bpp), dim3(THREADS), 0, stream,
                           pxy, pxz, pyz, pxt, pyt, pzt, tables, sidx, encW, npts, bpp);
        hipLaunchKernelGGL(mlp_mfma_k, dim3(npts / (64 * MLP_TILES)), dim3(256), 0, stream,
                           encW, W1B, W2B, W3, out, npts);
    } else {
        hipLaunchKernelGGL(fused_mono, dim3(bpp), dim3(THREADS), 0, stream,
                           pxy, pxz, pyz, pxt, pyt, pzt, tables, W1, W2, W3, out, npts);
    }
}

// Round 7
// 1470.840 us; speedup vs baseline: 1.6428x; 1.0072x over previous
//
#include <hip/hip_runtime.h>

#define THREADS 256
#define LVLS 16
#define TSZ 524288u
#define TMASK 524287u
#define PRIME1 2654435761u
#define HID 64
#define NBIN 16384         // 128x128 Morton bins per plane
#define ENC_STRIDE 104     // uint words per point: 96 hash + 6 coord + 2 pad (208 bf16)
#define MLP_TILES 8

typedef __attribute__((ext_vector_type(8))) short bf16x8;
typedef __attribute__((ext_vector_type(4))) float f32x4;

constexpr float resf(int l) { double r = 16.0; for (int i = 0; i < l; ++i) r *= 1.3819; return (float)r; }

__device__ __constant__ float c_RES[LVLS] = {
    resf(0),  resf(1),  resf(2),  resf(3),
    resf(4),  resf(5),  resf(6),  resf(7),
    resf(8),  resf(9),  resf(10), resf(11),
    resf(12), resf(13), resf(14), resf(15)
};

__device__ __forceinline__ unsigned packbf2(float a, float b) {
    unsigned ua = __float_as_uint(a), ub = __float_as_uint(b);
    ua += 0x7FFFu + ((ua >> 16) & 1u);   // RNE to bf16
    ub += 0x7FFFu + ((ub >> 16) & 1u);
    return (ua >> 16) | (ub & 0xFFFF0000u);
}

__device__ __forceinline__ unsigned short bf16rne(float f) {
    unsigned u = __float_as_uint(f);
    u += 0x7FFFu + ((u >> 16) & 1u);
    return (unsigned short)(u >> 16);
}

__device__ __forceinline__ unsigned part1by1(unsigned v) {
    v &= 0xFFu;
    v = (v | (v << 4)) & 0x0F0Fu;
    v = (v | (v << 2)) & 0x3333u;
    v = (v | (v << 1)) & 0x5555u;
    return v;
}

__device__ __forceinline__ float2 load_pt(int s, int i,
    const float* pxy, const float* pxz, const float* pyz,
    const float* pxt, const float* pyt, const float* pzt)
{
    switch (s) {
        case 0: return ((const float2*)pxy)[i];
        case 1: return ((const float2*)pxz)[i];
        case 2: return ((const float2*)pyz)[i];
        case 3: return ((const float2*)pxt)[i];
        case 4: return ((const float2*)pyt)[i];
        default: return ((const float2*)pzt)[i];
    }
}

__device__ __forceinline__ unsigned bin_key(float2 pt) {
    const int xb = min(127, (int)(pt.x * 128.f));
    const int yb = min(127, (int)(pt.y * 128.f));
    return part1by1((unsigned)xb) | (part1by1((unsigned)yb) << 1);   // < 16384
}

// ---------------- weight prep: pack W1/W2 into bf16 MFMA B-fragment order ----------------
__global__ __launch_bounds__(256) void pack_w1_k(const float* __restrict__ W1,
                                                 unsigned short* __restrict__ W1B)
{
    const int e = blockIdx.x * 256 + threadIdx.x;
    if (e >= 7 * 4 * 64 * 8) return;
    const int j = e & 7;
    const int lane = (e >> 3) & 63;
    const int n = (e >> 9) & 3;
    const int t = e >> 11;
    const int k = t * 32 + ((lane >> 4) << 3) + j;
    const int col = n * 16 + (lane & 15);
    float v = 0.f;
    if (k < 192) { const int s = k >> 5, rem = k & 31; v = W1[(s * 34 + rem) * HID + col]; }
    else if (k < 204) { const int q = k - 192; v = W1[((q >> 1) * 34 + 32 + (q & 1)) * HID + col]; }
    W1B[e] = bf16rne(v);
}

__global__ __launch_bounds__(256) void pack_w2_k(const float* __restrict__ W2,
                                                 unsigned short* __restrict__ W2B)
{
    const int e = blockIdx.x * 256 + threadIdx.x;
    if (e >= 2 * 4 * 64 * 8) return;
    const int j = e & 7;
    const int lane = (e >> 3) & 63;
    const int n = (e >> 9) & 3;
    const int t = e >> 11;
    const int k = t * 32 + ((lane >> 4) << 3) + j;
    const int col = n * 16 + (lane & 15);
    W2B[e] = bf16rne(W2[k * HID + col]);
}

// ---------------- sort pipeline ----------------
__global__ void zero_hist_k(int* __restrict__ hist) {
    const int i = blockIdx.x * blockDim.x + threadIdx.x;
    if (i < 6 * NBIN) hist[i] = 0;
}

__global__ __launch_bounds__(THREADS) void hist_k(
    const float* __restrict__ pxy, const float* __restrict__ pxz,
    const float* __restrict__ pyz, const float* __restrict__ pxt,
    const float* __restrict__ pyt, const float* __restrict__ pzt,
    int* __restrict__ hist, unsigned short* __restrict__ keys, int npts, int bpp)
{
    const int s = blockIdx.x / bpp;
    const int i = (blockIdx.x - s * bpp) * THREADS + threadIdx.x;
    if (i >= npts) return;
    const float2 pt = load_pt(s, i, pxy, pxz, pyz, pxt, pyt, pzt);
    const unsigned key = bin_key(pt);
    keys[(size_t)s * npts + i] = (unsigned short)key;
    atomicAdd(&hist[s * NBIN + key], 1);
}

// in-place: cursors overwrite hist. 1024 threads x 16 bins each.
__global__ __launch_bounds__(1024) void scan_k(int* __restrict__ hist)
{
    __shared__ int sb[1024];
    const int p = blockIdx.x;
    const int t = threadIdx.x;
    const int base = p * NBIN + t * 16;
    int h[16], pre[16];
    int run = 0;
    #pragma unroll
    for (int i = 0; i < 16; ++i) { h[i] = hist[base + i]; pre[i] = run; run += h[i]; }
    sb[t] = run;
    __syncthreads();
    for (int off = 1; off < 1024; off <<= 1) {
        const int v = (t >= off) ? sb[t - off] : 0;
        __syncthreads();
        sb[t] += v;
        __syncthreads();
    }
    const int start = sb[t] - run;   // exclusive within plane
    #pragma unroll
    for (int i = 0; i < 16; ++i) hist[base + i] = start + pre[i];
}

__global__ __launch_bounds__(THREADS) void scatter_k(
    const unsigned short* __restrict__ keys, int* __restrict__ curs,
    int* __restrict__ sidx, int npts, int bpp)
{
    const int s = blockIdx.x / bpp;
    const int i = (blockIdx.x - s * bpp) * THREADS + threadIdx.x;
    if (i >= npts) return;
    const unsigned key = keys[(size_t)s * npts + i];
    const int pos = atomicAdd(&curs[s * NBIN + key], 1);
    sidx[(size_t)s * npts + pos] = i;
}

// ---------------- sorted hash-grid gather -> bf16 enc (stride 104 words) ----------------
__global__ __launch_bounds__(THREADS, 6) void gather_sorted_k(
    const float* __restrict__ pxy, const float* __restrict__ pxz,
    const float* __restrict__ pyz, const float* __restrict__ pxt,
    const float* __restrict__ pyt, const float* __restrict__ pzt,
    const float* __restrict__ tables, const int* __restrict__ sidx,
    unsigned* __restrict__ encW, int npts, int bpp)
{
    int bid = blockIdx.x;
    const int G = gridDim.x;
    if ((G & 7) == 0) {                       // XCD-aware chunked swizzle (bijective)
        const int chunk = G >> 3;
        bid = (bid & 7) * chunk + (bid >> 3);
    }
    const int s = bid / bpp;
    const int i = (bid - s * bpp) * THREADS + threadIdx.x;
    if (i >= npts) return;

    const int orig = sidx[(size_t)s * npts + i];
    const float2 pt = load_pt(s, orig, pxy, pxz, pyz, pxt, pyt, pzt);
    const float2* tbase = ((const float2*)tables) + (size_t)s * LVLS * TSZ;

    unsigned ew[LVLS];
    #pragma unroll
    for (int l = 0; l < LVLS; ++l) {
        const float r = c_RES[l];
        const float fx = pt.x * r, fy = pt.y * r;
        const float flx = floorf(fx), fly = floorf(fy);
        const float wx = fx - flx, wy = fy - fly;
        const unsigned x0 = (unsigned)(int)flx;
        const unsigned y0 = (unsigned)(int)fly;
        const unsigned hy0 = y0 * PRIME1;
        const unsigned hy1 = hy0 + PRIME1;
        const float2* tab = tbase + (size_t)l * TSZ;
        const float2 f00 = tab[(x0 ^ hy0) & TMASK];
        const float2 f10 = tab[((x0 + 1u) ^ hy0) & TMASK];
        const float2 f01 = tab[(x0 ^ hy1) & TMASK];
        const float2 f11 = tab[((x0 + 1u) ^ hy1) & TMASK];
        const float w00 = (1.f - wx) * (1.f - wy);
        const float w10 = wx * (1.f - wy);
        const float w01 = (1.f - wx) * wy;
        const float w11 = wx * wy;
        const float e0 = f00.x * w00 + f10.x * w10 + f01.x * w01 + f11.x * w11;
        const float e1 = f00.y * w00 + f10.y * w10 + f01.y * w01 + f11.y * w11;
        ew[l] = packbf2(e0, e1);
    }

    unsigned* rowp = encW + (size_t)orig * ENC_STRIDE;
    uint4* dst = (uint4*)(rowp + s * LVLS);
    dst[0] = make_uint4(ew[0],  ew[1],  ew[2],  ew[3]);
    dst[1] = make_uint4(ew[4],  ew[5],  ew[6],  ew[7]);
    dst[2] = make_uint4(ew[8],  ew[9],  ew[10], ew[11]);
    dst[3] = make_uint4(ew[12], ew[13], ew[14], ew[15]);
    rowp[96 + s] = packbf2(pt.x, pt.y);          // coord features k=192+2s,193+2s
    if (s == 0) { rowp[102] = 0u; rowp[103] = 0u; }  // pad k=204..207
}

// ---------------- MFMA MLP (unchanged from R6) ----------------
__global__ __launch_bounds__(256, 2) void mlp_mfma_k(
    const unsigned* __restrict__ encW, const unsigned short* __restrict__ W1Bg,
    const unsigned short* __restrict__ W2Bg, const float* __restrict__ W3,
    float* __restrict__ out, int npts)
{
    __shared__ uint4 sW1B[1792];          // 7 ksteps * 4 ntiles * 64 lanes * 16B
    __shared__ uint4 sW2B[512];
    __shared__ float sW3[192];
    __shared__ unsigned short sH1[4][1024];  // per-wave 16x64 bf16, XOR-swizzled

    const int tid = threadIdx.x;
    for (int i = tid; i < 1792; i += 256) sW1B[i] = ((const uint4*)W1Bg)[i];
    for (int i = tid; i < 512; i += 256) sW2B[i] = ((const uint4*)W2Bg)[i];
    for (int i = tid; i < 192; i += 256) sW3[i] = W3[i];
    __syncthreads();

    const int w = tid >> 6, lane = tid & 63;
    const int row = lane & 15, g = lane >> 4;
    const int blk0 = blockIdx.x * (64 * MLP_TILES);

    for (int it = 0; it < MLP_TILES; ++it) {
        const int p0 = blk0 + (it * 4 + w) * 16;
        if (p0 + 16 > npts) { __syncthreads(); __syncthreads(); continue; }

        f32x4 acc0 = {0.f,0.f,0.f,0.f}, acc1 = acc0, acc2_ = acc0, acc3 = acc0;
        const unsigned* arow = encW + (size_t)(p0 + row) * ENC_STRIDE;
        #pragma unroll
        for (int t = 0; t < 7; ++t) {
            const int gw = (t == 6) ? (g & 1) : g;   // last kstep: valid words only; B=0 beyond k=207
            const uint4 av = *(const uint4*)(arow + t * 16 + gw * 4);
            const bf16x8 a = *(const bf16x8*)&av;
            acc0 = __builtin_amdgcn_mfma_f32_16x16x32_bf16(a, *(const bf16x8*)&sW1B[(t*4+0)*64 + lane], acc0, 0, 0, 0);
            acc1 = __builtin_amdgcn_mfma_f32_16x16x32_bf16(a, *(const bf16x8*)&sW1B[(t*4+1)*64 + lane], acc1, 0, 0, 0);
            acc2_ = __builtin_amdgcn_mfma_f32_16x16x32_bf16(a, *(const bf16x8*)&sW1B[(t*4+2)*64 + lane], acc2_, 0, 0, 0);
            acc3 = __builtin_amdgcn_mfma_f32_16x16x32_bf16(a, *(const bf16x8*)&sW1B[(t*4+3)*64 + lane], acc3, 0, 0, 0);
        }

        #pragma unroll
        for (int r = 0; r < 4; ++r) {
            const int rr = g * 4 + r;
            const int base = rr * 64;
            const int swz = (rr & 7) << 3;
            sH1[w][(base + 0 * 16 + row) ^ swz] = bf16rne(fmaxf(acc0[r], 0.f));
            sH1[w][(base + 1 * 16 + row) ^ swz] = bf16rne(fmaxf(acc1[r], 0.f));
            sH1[w][(base + 2 * 16 + row) ^ swz] = bf16rne(fmaxf(acc2_[r], 0.f));
            sH1[w][(base + 3 * 16 + row) ^ swz] = bf16rne(fmaxf(acc3[r], 0.f));
        }
        __syncthreads();

        f32x4 b0 = {0.f,0.f,0.f,0.f}, b1 = b0, b2 = b0, b3 = b0;
        #pragma unroll
        for (int t = 0; t < 2; ++t) {
            const int kidx = (row * 64 + t * 32 + g * 8) ^ ((row & 7) << 3);
            const bf16x8 a2 = *(const bf16x8*)&sH1[w][kidx];
            b0 = __builtin_amdgcn_mfma_f32_16x16x32_bf16(a2, *(const bf16x8*)&sW2B[(t*4+0)*64 + lane], b0, 0, 0, 0);
            b1 = __builtin_amdgcn_mfma_f32_16x16x32_bf16(a2, *(const bf16x8*)&sW2B[(t*4+1)*64 + lane], b1, 0, 0, 0);
            b2 = __builtin_amdgcn_mfma_f32_16x16x32_bf16(a2, *(const bf16x8*)&sW2B[(t*4+2)*64 + lane], b2, 0, 0, 0);
            b3 = __builtin_amdgcn_mfma_f32_16x16x32_bf16(a2, *(const bf16x8*)&sW2B[(t*4+3)*64 + lane], b3, 0, 0, 0);
        }

        float o[4][3];
        #pragma unroll
        for (int r = 0; r < 4; ++r) { o[r][0] = 0.f; o[r][1] = 0.f; o[r][2] = 0.f; }
        #pragma unroll
        for (int n = 0; n < 4; ++n) {
            const int m = n * 16 + row;
            const float w30 = sW3[m * 3 + 0], w31 = sW3[m * 3 + 1], w32 = sW3[m * 3 + 2];
            const f32x4 bb = (n == 0) ? b0 : (n == 1) ? b1 : (n == 2) ? b2 : b3;
            #pragma unroll
            for (int r = 0; r < 4; ++r) {
                const float h = fmaxf(bb[r], 0.f);
                o[r][0] += h * w30; o[r][1] += h * w31; o[r][2] += h * w32;
            }
        }
        #pragma unroll
        for (int m = 1; m < 16; m <<= 1) {
            #pragma unroll
            for (int r = 0; r < 4; ++r) {
                o[r][0] += __shfl_xor(o[r][0], m, 64);
                o[r][1] += __shfl_xor(o[r][1], m, 64);
                o[r][2] += __shfl_xor(o[r][2], m, 64);
            }
        }
        if (row == 0) {
            #pragma unroll
            for (int r = 0; r < 4; ++r) {
                const int p = p0 + g * 4 + r;
                out[p * 3 + 0] = o[r][0];
                out[p * 3 + 1] = o[r][1];
                out[p * 3 + 2] = o[r][2];
            }
        }
        __syncthreads();   // WAR: reads done before next iter overwrites sH1
    }
}

// ---------------- Fallback: fused fp32 kernel (used only if ws too small) ----------------
__global__ __launch_bounds__(THREADS, 4) void fused_mono(
    const float* __restrict__ pxy, const float* __restrict__ pxz,
    const float* __restrict__ pyz, const float* __restrict__ pxt,
    const float* __restrict__ pyt, const float* __restrict__ pzt,
    const float* __restrict__ tables, const float* __restrict__ W1,
    const float* __restrict__ W2, const float* __restrict__ W3,
    float* __restrict__ out, int npts)
{
    const int gid = blockIdx.x * THREADS + threadIdx.x;

    float h1[HID];
    #pragma unroll
    for (int k = 0; k < HID; ++k) h1[k] = 0.f;

    #pragma unroll 1
    for (int s = 0; s < 6; ++s) {
        const float2 pt = load_pt(s, gid, pxy, pxz, pyz, pxt, pyt, pzt);
        const float px = pt.x, py = pt.y;
        const float2* tbase = ((const float2*)tables) + (size_t)s * LVLS * TSZ;
        const float* w1s = W1 + (s * 34) * HID;

        #pragma unroll 2
        for (int l = 0; l < LVLS; ++l) {
            const float r = c_RES[l];
            const float fx = px * r, fy = py * r;
            const float flx = floorf(fx), fly = floorf(fy);
            const float wx = fx - flx, wy = fy - fly;
            const unsigned x0 = (unsigned)(int)flx;
            const unsigned y0 = (unsigned)(int)fly;
            const unsigned hy0 = y0 * PRIME1;
            const unsigned hy1 = hy0 + PRIME1;
            const float2* tab = tbase + (size_t)l * TSZ;
            const float2 f00 = tab[(x0 ^ hy0) & TMASK];
            const float2 f10 = tab[((x0 + 1u) ^ hy0) & TMASK];
            const float2 f01 = tab[(x0 ^ hy1) & TMASK];
            const float2 f11 = tab[((x0 + 1u) ^ hy1) & TMASK];
            const float w00 = (1.f - wx) * (1.f - wy);
            const float w10 = wx * (1.f - wy);
            const float w01 = (1.f - wx) * wy;
            const float w11 = wx * wy;
            const float e0 = f00.x * w00 + f10.x * w10 + f01.x * w01 + f11.x * w11;
            const float e1 = f00.y * w00 + f10.y * w10 + f01.y * w01 + f11.y * w11;
            const float4* wa = (const float4*)(w1s + (2 * l) * HID);
            const float4* wb = wa + 16;
            #pragma unroll
            for (int q = 0; q < 16; ++q) {
                const float4 a = wa[q];
                const float4 b = wb[q];
                h1[4*q+0] += e0 * a.x + e1 * b.x;
                h1[4*q+1] += e0 * a.y + e1 * b.y;
                h1[4*q+2] += e0 * a.z + e1 * b.z;
                h1[4*q+3] += e0 * a.w + e1 * b.w;
            }
        }
        const float4* wa = (const float4*)(w1s + 32 * HID);
        const float4* wb = wa + 16;
        #pragma unroll
        for (int q = 0; q < 16; ++q) {
            const float4 a = wa[q];
            const float4 b = wb[q];
            h1[4*q+0] += px * a.x + py * b.x;
            h1[4*q+1] += px * a.y + py * b.y;
            h1[4*q+2] += px * a.z + py * b.z;
            h1[4*q+3] += px * a.w + py * b.w;
        }
    }

    #pragma unroll
    for (int k = 0; k < HID; ++k) h1[k] = fmaxf(h1[k], 0.f);

    float o0 = 0.f, o1 = 0.f, o2 = 0.f;
    #pragma unroll 1
    for (int c = 0; c < 4; ++c) {
        float t[16];
        #pragma unroll
        for (int i = 0; i < 16; ++i) t[i] = 0.f;
        #pragma unroll
        for (int k = 0; k < HID; ++k) {
            const float4* w2r = (const float4*)(W2 + k * HID + c * 16);
            const float hk = h1[k];
            const float4 a = w2r[0];
            const float4 b = w2r[1];
            const float4 d = w2r[2];
            const float4 e = w2r[3];
            t[0]  += hk * a.x;  t[1]  += hk * a.y;  t[2]  += hk * a.z;  t[3]  += hk * a.w;
            t[4]  += hk * b.x;  t[5]  += hk * b.y;  t[6]  += hk * b.z;  t[7]  += hk * b.w;
            t[8]  += hk * d.x;  t[9]  += hk * d.y;  t[10] += hk * d.z;  t[11] += hk * d.w;
            t[12] += hk * e.x;  t[13] += hk * e.y;  t[14] += hk * e.z;  t[15] += hk * e.w;
        }
        #pragma unroll
        for (int i = 0; i < 16; ++i) {
            const float tt = fmaxf(t[i], 0.f);
            const int m = c * 16 + i;
            o0 += tt * W3[m * 3 + 0];
            o1 += tt * W3[m * 3 + 1];
            o2 += tt * W3[m * 3 + 2];
        }
    }

    if (gid < npts) {
        out[3 * gid + 0] = o0;
        out[3 * gid + 1] = o1;
        out[3 * gid + 2] = o2;
    }
}

extern "C" void kernel_launch(void* const* d_in, const int* in_sizes, int n_in,
                              void* d_out, int out_size, void* d_ws, size_t ws_size,
                              hipStream_t stream)
{
    const float* pxy = (const float*)d_in[0];
    const float* pxz = (const float*)d_in[1];
    const float* pyz = (const float*)d_in[2];
    const float* pxt = (const float*)d_in[3];
    const float* pyt = (const float*)d_in[4];
    const float* pzt = (const float*)d_in[5];
    const float* tables = (const float*)d_in[6];
    const float* W1 = (const float*)d_in[7];
    const float* W2 = (const float*)d_in[8];
    const float* W3 = (const float*)d_in[9];
    float* out = (float*)d_out;

    const int npts = in_sizes[0] / 2;
    const int bpp = (npts + THREADS - 1) / THREADS;

    // workspace layout: [W1B 28KB][W2B 8KB] [sidx 24MB @64KB] [enc 416MB]
    // transient keys (12MB) + hist/curs (384KB) live INSIDE the enc region
    // (consumed by scatter before gather writes enc).
    const size_t off_w1b  = 0;
    const size_t off_w2b  = 28672;
    const size_t off_sidx = 65536;
    size_t off_enc = off_sidx + (size_t)6 * npts * 4;
    off_enc = (off_enc + 127) & ~(size_t)127;
    const size_t need = off_enc + (size_t)npts * ENC_STRIDE * 4;

    if (ws_size >= need && (npts % (64 * MLP_TILES)) == 0 && npts % THREADS == 0) {
        char* ws = (char*)d_ws;
        unsigned short* W1B = (unsigned short*)(ws + off_w1b);
        unsigned short* W2B = (unsigned short*)(ws + off_w2b);
        int* sidx = (int*)(ws + off_sidx);
        unsigned* encW = (unsigned*)(ws + off_enc);
        unsigned short* keys = (unsigned short*)encW;                       // 12 MB
        int* hist = (int*)((char*)encW + (size_t)6 * npts * 2);             // 384 KB

        hipLaunchKernelGGL(zero_hist_k, dim3((6 * NBIN + THREADS - 1) / THREADS),
                           dim3(THREADS), 0, stream, hist);
        hipLaunchKernelGGL(hist_k, dim3(6 * bpp), dim3(THREADS), 0, stream,
                           pxy, pxz, pyz, pxt, pyt, pzt, hist, keys, npts, bpp);
        hipLaunchKernelGGL(scan_k, dim3(6), dim3(1024), 0, stream, hist);
        hipLaunchKernelGGL(pack_w1_k, dim3(56), dim3(256), 0, stream, W1, W1B);
        hipLaunchKernelGGL(pack_w2_k, dim3(16), dim3(256), 0, stream, W2, W2B);
        hipLaunchKernelGGL(scatter_k, dim3(6 * bpp), dim3(THREADS), 0, stream,
                           keys, hist, sidx, npts, bpp);
        hipLaunchKernelGGL(gather_sorted_k, dim3(6 * bpp), dim3(THREADS), 0, stream,
                           pxy, pxz, pyz, pxt, pyt, pzt, tables, sidx, encW, npts, bpp);
        hipLaunchKernelGGL(mlp_mfma_k, dim3(npts / (64 * MLP_TILES)), dim3(256), 0, stream,
                           encW, W1B, W2B, W3, out, npts);
    } else {
        hipLaunchKernelGGL(fused_mono, dim3(bpp), dim3(THREADS), 0, stream,
                           pxy, pxz, pyz, pxt, pyt, pzt, tables, W1, W2, W3, out, npts);
    }
}

// Round 8
// 1254.721 us; speedup vs baseline: 1.9257x; 1.1722x over previous
//
#include <hip/hip_runtime.h>

#define THREADS 256
#define LVLS 16
#define TSZ 524288u
#define TMASK 524287u
#define PRIME1 2654435761u
#define HID 64
#define NBIN 16384         // 128x128 Morton bins per plane
#define MLP_TILES 8

typedef __attribute__((ext_vector_type(8))) short bf16x8;
typedef __attribute__((ext_vector_type(4))) float f32x4;

constexpr float resf(int l) { double r = 16.0; for (int i = 0; i < l; ++i) r *= 1.3819; return (float)r; }

__device__ __constant__ float c_RES[LVLS] = {
    resf(0),  resf(1),  resf(2),  resf(3),
    resf(4),  resf(5),  resf(6),  resf(7),
    resf(8),  resf(9),  resf(10), resf(11),
    resf(12), resf(13), resf(14), resf(15)
};

__device__ __forceinline__ unsigned packbf2(float a, float b) {
    unsigned ua = __float_as_uint(a), ub = __float_as_uint(b);
    ua += 0x7FFFu + ((ua >> 16) & 1u);   // RNE to bf16
    ub += 0x7FFFu + ((ub >> 16) & 1u);
    return (ua >> 16) | (ub & 0xFFFF0000u);
}

__device__ __forceinline__ unsigned short bf16rne(float f) {
    unsigned u = __float_as_uint(f);
    u += 0x7FFFu + ((u >> 16) & 1u);
    return (unsigned short)(u >> 16);
}

__device__ __forceinline__ unsigned part1by1(unsigned v) {
    v &= 0xFFu;
    v = (v | (v << 4)) & 0x0F0Fu;
    v = (v | (v << 2)) & 0x3333u;
    v = (v | (v << 1)) & 0x5555u;
    return v;
}

__device__ __forceinline__ float2 load_pt(int s, int i,
    const float* pxy, const float* pxz, const float* pyz,
    const float* pxt, const float* pyt, const float* pzt)
{
    switch (s) {
        case 0: return ((const float2*)pxy)[i];
        case 1: return ((const float2*)pxz)[i];
        case 2: return ((const float2*)pyz)[i];
        case 3: return ((const float2*)pxt)[i];
        case 4: return ((const float2*)pyt)[i];
        default: return ((const float2*)pzt)[i];
    }
}

__device__ __forceinline__ unsigned bin_key(float2 pt) {
    const int xb = min(127, (int)(pt.x * 128.f));
    const int yb = min(127, (int)(pt.y * 128.f));
    return part1by1((unsigned)xb) | (part1by1((unsigned)yb) << 1);   // < 16384
}

// ---------------- weight prep: pack W1/W2 into bf16 MFMA B-fragment order ----------------
__global__ __launch_bounds__(256) void pack_w1_k(const float* __restrict__ W1,
                                                 unsigned short* __restrict__ W1B)
{
    const int e = blockIdx.x * 256 + threadIdx.x;
    if (e >= 7 * 4 * 64 * 8) return;
    const int j = e & 7;
    const int lane = (e >> 3) & 63;
    const int n = (e >> 9) & 3;
    const int t = e >> 11;
    const int k = t * 32 + ((lane >> 4) << 3) + j;
    const int col = n * 16 + (lane & 15);
    float v = 0.f;
    if (k < 192) { const int s = k >> 5, rem = k & 31; v = W1[(s * 34 + rem) * HID + col]; }
    else if (k < 204) { const int q = k - 192; v = W1[((q >> 1) * 34 + 32 + (q & 1)) * HID + col]; }
    W1B[e] = bf16rne(v);
}

__global__ __launch_bounds__(256) void pack_w2_k(const float* __restrict__ W2,
                                                 unsigned short* __restrict__ W2B)
{
    const int e = blockIdx.x * 256 + threadIdx.x;
    if (e >= 2 * 4 * 64 * 8) return;
    const int j = e & 7;
    const int lane = (e >> 3) & 63;
    const int n = (e >> 9) & 3;
    const int t = e >> 11;
    const int k = t * 32 + ((lane >> 4) << 3) + j;
    const int col = n * 16 + (lane & 15);
    W2B[e] = bf16rne(W2[k * HID + col]);
}

// ---------------- sort pipeline ----------------
__global__ void zero_hist_k(int* __restrict__ hist) {
    const int i = blockIdx.x * blockDim.x + threadIdx.x;
    if (i < 6 * NBIN) hist[i] = 0;
}

__global__ __launch_bounds__(THREADS) void hist_k(
    const float* __restrict__ pxy, const float* __restrict__ pxz,
    const float* __restrict__ pyz, const float* __restrict__ pxt,
    const float* __restrict__ pyt, const float* __restrict__ pzt,
    int* __restrict__ hist, unsigned short* __restrict__ keys, int npts, int bpp)
{
    const int s = blockIdx.x / bpp;
    const int i = (blockIdx.x - s * bpp) * THREADS + threadIdx.x;
    if (i >= npts) return;
    const float2 pt = load_pt(s, i, pxy, pxz, pyz, pxt, pyt, pzt);
    const unsigned key = bin_key(pt);
    keys[(size_t)s * npts + i] = (unsigned short)key;
    atomicAdd(&hist[s * NBIN + key], 1);
}

// in-place: cursors overwrite hist. 1024 threads x 16 bins each.
__global__ __launch_bounds__(1024) void scan_k(int* __restrict__ hist)
{
    __shared__ int sb[1024];
    const int p = blockIdx.x;
    const int t = threadIdx.x;
    const int base = p * NBIN + t * 16;
    int h[16], pre[16];
    int run = 0;
    #pragma unroll
    for (int i = 0; i < 16; ++i) { h[i] = hist[base + i]; pre[i] = run; run += h[i]; }
    sb[t] = run;
    __syncthreads();
    for (int off = 1; off < 1024; off <<= 1) {
        const int v = (t >= off) ? sb[t - off] : 0;
        __syncthreads();
        sb[t] += v;
        __syncthreads();
    }
    const int start = sb[t] - run;   // exclusive within plane
    #pragma unroll
    for (int i = 0; i < 16; ++i) hist[base + i] = start + pre[i];
}

// writes both directions of the permutation: sidx (sorted->orig, scattered)
// and inv (orig->sorted, coalesced).
__global__ __launch_bounds__(THREADS) void scatter_k(
    const unsigned short* __restrict__ keys, int* __restrict__ curs,
    int* __restrict__ sidx, int* __restrict__ inv, int npts, int bpp)
{
    const int s = blockIdx.x / bpp;
    const int i = (blockIdx.x - s * bpp) * THREADS + threadIdx.x;
    if (i >= npts) return;
    const unsigned key = keys[(size_t)s * npts + i];
    const int pos = atomicAdd(&curs[s * NBIN + key], 1);
    sidx[(size_t)s * npts + pos] = i;
    inv[(size_t)s * npts + i] = pos;
}

// ---------------- sorted hash-grid gather -> bf16 enc rows (sorted order, 64B/row) ----------------
// Batched: 4 levels' 16 corner loads issued together for deep MLP.
__global__ __launch_bounds__(THREADS, 5) void gather_sorted_k(
    const float* __restrict__ pxy, const float* __restrict__ pxz,
    const float* __restrict__ pyz, const float* __restrict__ pxt,
    const float* __restrict__ pyt, const float* __restrict__ pzt,
    const float* __restrict__ tables, const int* __restrict__ sidx,
    unsigned* __restrict__ encP, int npts, int bpp)
{
    int bid = blockIdx.x;
    const int G = gridDim.x;
    if ((G & 7) == 0) {                       // XCD-aware chunked swizzle (bijective)
        const int chunk = G >> 3;
        bid = (bid & 7) * chunk + (bid >> 3);
    }
    const int s = bid / bpp;
    const int i = (bid - s * bpp) * THREADS + threadIdx.x;
    if (i >= npts) return;

    const int orig = sidx[(size_t)s * npts + i];
    const float2 pt = load_pt(s, orig, pxy, pxz, pyz, pxt, pyt, pzt);
    const float2* tab0 = ((const float2*)tables) + (size_t)s * LVLS * TSZ;

    unsigned ew[LVLS];
    #pragma unroll
    for (int g4 = 0; g4 < 4; ++g4) {
        float2 cor[16];
        float wxs[4], wys[4];
        #pragma unroll
        for (int q = 0; q < 4; ++q) {
            const int l = g4 * 4 + q;
            const float r = c_RES[l];
            const float fx = pt.x * r, fy = pt.y * r;
            const float flx = floorf(fx), fly = floorf(fy);
            wxs[q] = fx - flx; wys[q] = fy - fly;
            const unsigned x0 = (unsigned)(int)flx;
            const unsigned y0 = (unsigned)(int)fly;
            const unsigned hy0 = y0 * PRIME1;
            const unsigned hy1 = hy0 + PRIME1;
            const float2* tab = tab0 + (size_t)l * TSZ;
            cor[q * 4 + 0] = tab[(x0 ^ hy0) & TMASK];
            cor[q * 4 + 1] = tab[((x0 + 1u) ^ hy0) & TMASK];
            cor[q * 4 + 2] = tab[(x0 ^ hy1) & TMASK];
            cor[q * 4 + 3] = tab[((x0 + 1u) ^ hy1) & TMASK];
        }
        #pragma unroll
        for (int q = 0; q < 4; ++q) {
            const float wx = wxs[q], wy = wys[q];
            const float w00 = (1.f - wx) * (1.f - wy);
            const float w10 = wx * (1.f - wy);
            const float w01 = (1.f - wx) * wy;
            const float w11 = wx * wy;
            const float e0 = cor[q*4+0].x * w00 + cor[q*4+1].x * w10 + cor[q*4+2].x * w01 + cor[q*4+3].x * w11;
            const float e1 = cor[q*4+0].y * w00 + cor[q*4+1].y * w10 + cor[q*4+2].y * w01 + cor[q*4+3].y * w11;
            ew[g4 * 4 + q] = packbf2(e0, e1);
        }
    }

    // coalesced 64B row write at SORTED position
    uint4* dst = (uint4*)(encP + ((size_t)s * npts + i) * 16);
    dst[0] = make_uint4(ew[0],  ew[1],  ew[2],  ew[3]);
    dst[1] = make_uint4(ew[4],  ew[5],  ew[6],  ew[7]);
    dst[2] = make_uint4(ew[8],  ew[9],  ew[10], ew[11]);
    dst[3] = make_uint4(ew[12], ew[13], ew[14], ew[15]);
}

// ---------------- MFMA MLP: A gathered from per-plane sorted enc via inv ----------------
__global__ __launch_bounds__(256, 2) void mlp_mfma_k(
    const float* __restrict__ pxy, const float* __restrict__ pxz,
    const float* __restrict__ pyz, const float* __restrict__ pxt,
    const float* __restrict__ pyt, const float* __restrict__ pzt,
    const unsigned* __restrict__ encP, const int* __restrict__ inv,
    const unsigned short* __restrict__ W1Bg, const unsigned short* __restrict__ W2Bg,
    const float* __restrict__ W3, float* __restrict__ out, int npts)
{
    __shared__ uint4 sW1B[1792];          // 7 ksteps * 4 ntiles * 64 lanes * 16B
    __shared__ uint4 sW2B[512];
    __shared__ float sW3[192];
    __shared__ unsigned short sH1[4][1024];  // per-wave 16x64 bf16, XOR-swizzled

    const int tid = threadIdx.x;
    for (int i = tid; i < 1792; i += 256) sW1B[i] = ((const uint4*)W1Bg)[i];
    for (int i = tid; i < 512; i += 256) sW2B[i] = ((const uint4*)W2Bg)[i];
    for (int i = tid; i < 192; i += 256) sW3[i] = W3[i];
    __syncthreads();

    const int w = tid >> 6, lane = tid & 63;
    const int row = lane & 15, g = lane >> 4;
    const int blk0 = blockIdx.x * (64 * MLP_TILES);

    for (int it = 0; it < MLP_TILES; ++it) {
        const int p0 = blk0 + (it * 4 + w) * 16;
        if (p0 + 16 > npts) { __syncthreads(); __syncthreads(); continue; }

        const int p = p0 + row;
        // batch all A-fragment loads: 6 inv + 6 enc-gathers in flight together
        int ip[6];
        #pragma unroll
        for (int t = 0; t < 6; ++t) ip[t] = inv[(size_t)t * npts + p];
        uint4 av[6];
        #pragma unroll
        for (int t = 0; t < 6; ++t)
            av[t] = *(const uint4*)(encP + ((size_t)t * npts + ip[t]) * 16 + g * 4);

        // coord k-step fragment (k=192..207 valid; B zero-padded beyond 204)
        unsigned cw0 = 0, cw1 = 0, cw2 = 0, cw3 = 0;
        if (g == 0) {
            float2 c0 = load_pt(0, p, pxy, pxz, pyz, pxt, pyt, pzt);
            float2 c1 = load_pt(1, p, pxy, pxz, pyz, pxt, pyt, pzt);
            float2 c2 = load_pt(2, p, pxy, pxz, pyz, pxt, pyt, pzt);
            float2 c3 = load_pt(3, p, pxy, pxz, pyz, pxt, pyt, pzt);
            cw0 = packbf2(c0.x, c0.y); cw1 = packbf2(c1.x, c1.y);
            cw2 = packbf2(c2.x, c2.y); cw3 = packbf2(c3.x, c3.y);
        } else if (g == 1) {
            float2 c4 = load_pt(4, p, pxy, pxz, pyz, pxt, pyt, pzt);
            float2 c5 = load_pt(5, p, pxy, pxz, pyz, pxt, pyt, pzt);
            cw0 = packbf2(c4.x, c4.y); cw1 = packbf2(c5.x, c5.y);
        }
        const uint4 avc = make_uint4(cw0, cw1, cw2, cw3);

        f32x4 acc0 = {0.f,0.f,0.f,0.f}, acc1 = acc0, acc2_ = acc0, acc3 = acc0;
        #pragma unroll
        for (int t = 0; t < 6; ++t) {
            const bf16x8 a = *(const bf16x8*)&av[t];
            acc0 = __builtin_amdgcn_mfma_f32_16x16x32_bf16(a, *(const bf16x8*)&sW1B[(t*4+0)*64 + lane], acc0, 0, 0, 0);
            acc1 = __builtin_amdgcn_mfma_f32_16x16x32_bf16(a, *(const bf16x8*)&sW1B[(t*4+1)*64 + lane], acc1, 0, 0, 0);
            acc2_ = __builtin_amdgcn_mfma_f32_16x16x32_bf16(a, *(const bf16x8*)&sW1B[(t*4+2)*64 + lane], acc2_, 0, 0, 0);
            acc3 = __builtin_amdgcn_mfma_f32_16x16x32_bf16(a, *(const bf16x8*)&sW1B[(t*4+3)*64 + lane], acc3, 0, 0, 0);
        }
        {
            const bf16x8 a = *(const bf16x8*)&avc;
            acc0 = __builtin_amdgcn_mfma_f32_16x16x32_bf16(a, *(const bf16x8*)&sW1B[(6*4+0)*64 + lane], acc0, 0, 0, 0);
            acc1 = __builtin_amdgcn_mfma_f32_16x16x32_bf16(a, *(const bf16x8*)&sW1B[(6*4+1)*64 + lane], acc1, 0, 0, 0);
            acc2_ = __builtin_amdgcn_mfma_f32_16x16x32_bf16(a, *(const bf16x8*)&sW1B[(6*4+2)*64 + lane], acc2_, 0, 0, 0);
            acc3 = __builtin_amdgcn_mfma_f32_16x16x32_bf16(a, *(const bf16x8*)&sW1B[(6*4+3)*64 + lane], acc3, 0, 0, 0);
        }

        // D layout: col = lane&15, row(point) = g*4 + reg
        #pragma unroll
        for (int r = 0; r < 4; ++r) {
            const int rr = g * 4 + r;
            const int base = rr * 64;
            const int swz = (rr & 7) << 3;
            sH1[w][(base + 0 * 16 + row) ^ swz] = bf16rne(fmaxf(acc0[r], 0.f));
            sH1[w][(base + 1 * 16 + row) ^ swz] = bf16rne(fmaxf(acc1[r], 0.f));
            sH1[w][(base + 2 * 16 + row) ^ swz] = bf16rne(fmaxf(acc2_[r], 0.f));
            sH1[w][(base + 3 * 16 + row) ^ swz] = bf16rne(fmaxf(acc3[r], 0.f));
        }
        __syncthreads();

        f32x4 b0 = {0.f,0.f,0.f,0.f}, b1 = b0, b2 = b0, b3 = b0;
        #pragma unroll
        for (int t = 0; t < 2; ++t) {
            const int kidx = (row * 64 + t * 32 + g * 8) ^ ((row & 7) << 3);
            const bf16x8 a2 = *(const bf16x8*)&sH1[w][kidx];
            b0 = __builtin_amdgcn_mfma_f32_16x16x32_bf16(a2, *(const bf16x8*)&sW2B[(t*4+0)*64 + lane], b0, 0, 0, 0);
            b1 = __builtin_amdgcn_mfma_f32_16x16x32_bf16(a2, *(const bf16x8*)&sW2B[(t*4+1)*64 + lane], b1, 0, 0, 0);
            b2 = __builtin_amdgcn_mfma_f32_16x16x32_bf16(a2, *(const bf16x8*)&sW2B[(t*4+2)*64 + lane], b2, 0, 0, 0);
            b3 = __builtin_amdgcn_mfma_f32_16x16x32_bf16(a2, *(const bf16x8*)&sW2B[(t*4+3)*64 + lane], b3, 0, 0, 0);
        }

        float o[4][3];
        #pragma unroll
        for (int r = 0; r < 4; ++r) { o[r][0] = 0.f; o[r][1] = 0.f; o[r][2] = 0.f; }
        #pragma unroll
        for (int n = 0; n < 4; ++n) {
            const int m = n * 16 + row;
            const float w30 = sW3[m * 3 + 0], w31 = sW3[m * 3 + 1], w32 = sW3[m * 3 + 2];
            const f32x4 bb = (n == 0) ? b0 : (n == 1) ? b1 : (n == 2) ? b2 : b3;
            #pragma unroll
            for (int r = 0; r < 4; ++r) {
                const float h = fmaxf(bb[r], 0.f);
                o[r][0] += h * w30; o[r][1] += h * w31; o[r][2] += h * w32;
            }
        }
        #pragma unroll
        for (int m = 1; m < 16; m <<= 1) {
            #pragma unroll
            for (int r = 0; r < 4; ++r) {
                o[r][0] += __shfl_xor(o[r][0], m, 64);
                o[r][1] += __shfl_xor(o[r][1], m, 64);
                o[r][2] += __shfl_xor(o[r][2], m, 64);
            }
        }
        if (row == 0) {
            #pragma unroll
            for (int r = 0; r < 4; ++r) {
                const int pp = p0 + g * 4 + r;
                out[pp * 3 + 0] = o[r][0];
                out[pp * 3 + 1] = o[r][1];
                out[pp * 3 + 2] = o[r][2];
            }
        }
        __syncthreads();   // WAR: reads done before next iter overwrites sH1
    }
}

// ---------------- Fallback: fused fp32 kernel (used only if ws too small) ----------------
__global__ __launch_bounds__(THREADS, 4) void fused_mono(
    const float* __restrict__ pxy, const float* __restrict__ pxz,
    const float* __restrict__ pyz, const float* __restrict__ pxt,
    const float* __restrict__ pyt, const float* __restrict__ pzt,
    const float* __restrict__ tables, const float* __restrict__ W1,
    const float* __restrict__ W2, const float* __restrict__ W3,
    float* __restrict__ out, int npts)
{
    const int gid = blockIdx.x * THREADS + threadIdx.x;

    float h1[HID];
    #pragma unroll
    for (int k = 0; k < HID; ++k) h1[k] = 0.f;

    #pragma unroll 1
    for (int s = 0; s < 6; ++s) {
        const float2 pt = load_pt(s, gid, pxy, pxz, pyz, pxt, pyt, pzt);
        const float px = pt.x, py = pt.y;
        const float2* tbase = ((const float2*)tables) + (size_t)s * LVLS * TSZ;
        const float* w1s = W1 + (s * 34) * HID;

        #pragma unroll 2
        for (int l = 0; l < LVLS; ++l) {
            const float r = c_RES[l];
            const float fx = px * r, fy = py * r;
            const float flx = floorf(fx), fly = floorf(fy);
            const float wx = fx - flx, wy = fy - fly;
            const unsigned x0 = (unsigned)(int)flx;
            const unsigned y0 = (unsigned)(int)fly;
            const unsigned hy0 = y0 * PRIME1;
            const unsigned hy1 = hy0 + PRIME1;
            const float2* tab = tbase + (size_t)l * TSZ;
            const float2 f00 = tab[(x0 ^ hy0) & TMASK];
            const float2 f10 = tab[((x0 + 1u) ^ hy0) & TMASK];
            const float2 f01 = tab[(x0 ^ hy1) & TMASK];
            const float2 f11 = tab[((x0 + 1u) ^ hy1) & TMASK];
            const float w00 = (1.f - wx) * (1.f - wy);
            const float w10 = wx * (1.f - wy);
            const float w01 = (1.f - wx) * wy;
            const float w11 = wx * wy;
            const float e0 = f00.x * w00 + f10.x * w10 + f01.x * w01 + f11.x * w11;
            const float e1 = f00.y * w00 + f10.y * w10 + f01.y * w01 + f11.y * w11;
            const float4* wa = (const float4*)(w1s + (2 * l) * HID);
            const float4* wb = wa + 16;
            #pragma unroll
            for (int q = 0; q < 16; ++q) {
                const float4 a = wa[q];
                const float4 b = wb[q];
                h1[4*q+0] += e0 * a.x + e1 * b.x;
                h1[4*q+1] += e0 * a.y + e1 * b.y;
                h1[4*q+2] += e0 * a.z + e1 * b.z;
                h1[4*q+3] += e0 * a.w + e1 * b.w;
            }
        }
        const float4* wa = (const float4*)(w1s + 32 * HID);
        const float4* wb = wa + 16;
        #pragma unroll
        for (int q = 0; q < 16; ++q) {
            const float4 a = wa[q];
            const float4 b = wb[q];
            h1[4*q+0] += px * a.x + py * b.x;
            h1[4*q+1] += px * a.y + py * b.y;
            h1[4*q+2] += px * a.z + py * b.z;
            h1[4*q+3] += px * a.w + py * b.w;
        }
    }

    #pragma unroll
    for (int k = 0; k < HID; ++k) h1[k] = fmaxf(h1[k], 0.f);

    float o0 = 0.f, o1 = 0.f, o2 = 0.f;
    #pragma unroll 1
    for (int c = 0; c < 4; ++c) {
        float t[16];
        #pragma unroll
        for (int i = 0; i < 16; ++i) t[i] = 0.f;
        #pragma unroll
        for (int k = 0; k < HID; ++k) {
            const float4* w2r = (const float4*)(W2 + k * HID + c * 16);
            const float hk = h1[k];
            const float4 a = w2r[0];
            const float4 b = w2r[1];
            const float4 d = w2r[2];
            const float4 e = w2r[3];
            t[0]  += hk * a.x;  t[1]  += hk * a.y;  t[2]  += hk * a.z;  t[3]  += hk * a.w;
            t[4]  += hk * b.x;  t[5]  += hk * b.y;  t[6]  += hk * b.z;  t[7]  += hk * b.w;
            t[8]  += hk * d.x;  t[9]  += hk * d.y;  t[10] += hk * d.z;  t[11] += hk * d.w;
            t[12] += hk * e.x;  t[13] += hk * e.y;  t[14] += hk * e.z;  t[15] += hk * e.w;
        }
        #pragma unroll
        for (int i = 0; i < 16; ++i) {
            const float tt = fmaxf(t[i], 0.f);
            const int m = c * 16 + i;
            o0 += tt * W3[m * 3 + 0];
            o1 += tt * W3[m * 3 + 1];
            o2 += tt * W3[m * 3 + 2];
        }
    }

    if (gid < npts) {
        out[3 * gid + 0] = o0;
        out[3 * gid + 1] = o1;
        out[3 * gid + 2] = o2;
    }
}

extern "C" void kernel_launch(void* const* d_in, const int* in_sizes, int n_in,
                              void* d_out, int out_size, void* d_ws, size_t ws_size,
                              hipStream_t stream)
{
    const float* pxy = (const float*)d_in[0];
    const float* pxz = (const float*)d_in[1];
    const float* pyz = (const float*)d_in[2];
    const float* pxt = (const float*)d_in[3];
    const float* pyt = (const float*)d_in[4];
    const float* pzt = (const float*)d_in[5];
    const float* tables = (const float*)d_in[6];
    const float* W1 = (const float*)d_in[7];
    const float* W2 = (const float*)d_in[8];
    const float* W3 = (const float*)d_in[9];
    float* out = (float*)d_out;

    const int npts = in_sizes[0] / 2;
    const int bpp = (npts + THREADS - 1) / THREADS;

    // workspace layout: [W1B][W2B] [sidx 24MB][inv 24MB] [enc 384MB: 6 planes * npts * 64B]
    // transient keys (12MB) + hist (384KB) live INSIDE the enc region (consumed before gather).
    const size_t off_w1b  = 0;
    const size_t off_w2b  = 28672;
    const size_t off_sidx = 65536;
    const size_t off_inv  = off_sidx + (size_t)6 * npts * 4;
    size_t off_enc = off_inv + (size_t)6 * npts * 4;
    off_enc = (off_enc + 127) & ~(size_t)127;
    const size_t need = off_enc + (size_t)6 * npts * 64;

    if (ws_size >= need && (npts % (64 * MLP_TILES)) == 0 && npts % THREADS == 0) {
        char* ws = (char*)d_ws;
        unsigned short* W1B = (unsigned short*)(ws + off_w1b);
        unsigned short* W2B = (unsigned short*)(ws + off_w2b);
        int* sidx = (int*)(ws + off_sidx);
        int* inv  = (int*)(ws + off_inv);
        unsigned* encP = (unsigned*)(ws + off_enc);
        unsigned short* keys = (unsigned short*)encP;                       // 12 MB transient
        int* hist = (int*)((char*)encP + (size_t)6 * npts * 2);             // 384 KB transient

        hipLaunchKernelGGL(zero_hist_k, dim3((6 * NBIN + THREADS - 1) / THREADS),
                           dim3(THREADS), 0, stream, hist);
        hipLaunchKernelGGL(hist_k, dim3(6 * bpp), dim3(THREADS), 0, stream,
                           pxy, pxz, pyz, pxt, pyt, pzt, hist, keys, npts, bpp);
        hipLaunchKernelGGL(scan_k, dim3(6), dim3(1024), 0, stream, hist);
        hipLaunchKernelGGL(pack_w1_k, dim3(56), dim3(256), 0, stream, W1, W1B);
        hipLaunchKernelGGL(pack_w2_k, dim3(16), dim3(256), 0, stream, W2, W2B);
        hipLaunchKernelGGL(scatter_k, dim3(6 * bpp), dim3(THREADS), 0, stream,
                           keys, hist, sidx, inv, npts, bpp);
        hipLaunchKernelGGL(gather_sorted_k, dim3(6 * bpp), dim3(THREADS), 0, stream,
                           pxy, pxz, pyz, pxt, pyt, pzt, tables, sidx, encP, npts, bpp);
        hipLaunchKernelGGL(mlp_mfma_k, dim3(npts / (64 * MLP_TILES)), dim3(256), 0, stream,
                           pxy, pxz, pyz, pxt, pyt, pzt, encP, inv, W1B, W2B, W3, out, npts);
    } else {
        hipLaunchKernelGGL(fused_mono, dim3(bpp), dim3(THREADS), 0, stream,
                           pxy, pxz, pyz, pxt, pyt, pzt, tables, W1, W2, W3, out, npts);
    }
}

// Round 9
// 1223.047 us; speedup vs baseline: 1.9756x; 1.0259x over previous
//
#include <hip/hip_runtime.h>

#define THREADS 256
#define LVLS 16
#define TSZ 524288u
#define TMASK 524287u
#define PRIME1 2654435761u
#define HID 64
#define NBIN 16384         // 128x128 Morton bins per plane
#define MLP_TILES 8
#define SC_PPT 8           // scatter: points per thread

typedef __attribute__((ext_vector_type(8))) short bf16x8;
typedef __attribute__((ext_vector_type(4))) float f32x4;

constexpr float resf(int l) { double r = 16.0; for (int i = 0; i < l; ++i) r *= 1.3819; return (float)r; }

__device__ __constant__ float c_RES[LVLS] = {
    resf(0),  resf(1),  resf(2),  resf(3),
    resf(4),  resf(5),  resf(6),  resf(7),
    resf(8),  resf(9),  resf(10), resf(11),
    resf(12), resf(13), resf(14), resf(15)
};

__device__ __forceinline__ unsigned packbf2(float a, float b) {
    unsigned ua = __float_as_uint(a), ub = __float_as_uint(b);
    ua += 0x7FFFu + ((ua >> 16) & 1u);   // RNE to bf16
    ub += 0x7FFFu + ((ub >> 16) & 1u);
    return (ua >> 16) | (ub & 0xFFFF0000u);
}

__device__ __forceinline__ unsigned short bf16rne(float f) {
    unsigned u = __float_as_uint(f);
    u += 0x7FFFu + ((u >> 16) & 1u);
    return (unsigned short)(u >> 16);
}

__device__ __forceinline__ unsigned part1by1(unsigned v) {
    v &= 0xFFu;
    v = (v | (v << 4)) & 0x0F0Fu;
    v = (v | (v << 2)) & 0x3333u;
    v = (v | (v << 1)) & 0x5555u;
    return v;
}

__device__ __forceinline__ float2 load_pt(int s, int i,
    const float* pxy, const float* pxz, const float* pyz,
    const float* pxt, const float* pyt, const float* pzt)
{
    switch (s) {
        case 0: return ((const float2*)pxy)[i];
        case 1: return ((const float2*)pxz)[i];
        case 2: return ((const float2*)pyz)[i];
        case 3: return ((const float2*)pxt)[i];
        case 4: return ((const float2*)pyt)[i];
        default: return ((const float2*)pzt)[i];
    }
}

__device__ __forceinline__ unsigned bin_key(float2 pt) {
    const int xb = min(127, (int)(pt.x * 128.f));
    const int yb = min(127, (int)(pt.y * 128.f));
    return part1by1((unsigned)xb) | (part1by1((unsigned)yb) << 1);   // < 16384
}

// ---------------- weight prep: pack W1/W2 into bf16 MFMA B-fragment order ----------------
__global__ __launch_bounds__(256) void pack_w1_k(const float* __restrict__ W1,
                                                 unsigned short* __restrict__ W1B)
{
    const int e = blockIdx.x * 256 + threadIdx.x;
    if (e >= 7 * 4 * 64 * 8) return;
    const int j = e & 7;
    const int lane = (e >> 3) & 63;
    const int n = (e >> 9) & 3;
    const int t = e >> 11;
    const int k = t * 32 + ((lane >> 4) << 3) + j;
    const int col = n * 16 + (lane & 15);
    float v = 0.f;
    if (k < 192) { const int s = k >> 5, rem = k & 31; v = W1[(s * 34 + rem) * HID + col]; }
    else if (k < 204) { const int q = k - 192; v = W1[((q >> 1) * 34 + 32 + (q & 1)) * HID + col]; }
    W1B[e] = bf16rne(v);
}

__global__ __launch_bounds__(256) void pack_w2_k(const float* __restrict__ W2,
                                                 unsigned short* __restrict__ W2B)
{
    const int e = blockIdx.x * 256 + threadIdx.x;
    if (e >= 2 * 4 * 64 * 8) return;
    const int j = e & 7;
    const int lane = (e >> 3) & 63;
    const int n = (e >> 9) & 3;
    const int t = e >> 11;
    const int k = t * 32 + ((lane >> 4) << 3) + j;
    const int col = n * 16 + (lane & 15);
    W2B[e] = bf16rne(W2[k * HID + col]);
}

// ---------------- sort pipeline ----------------
__global__ void zero_hist_k(int* __restrict__ hist) {
    const int i = blockIdx.x * blockDim.x + threadIdx.x;
    if (i < 6 * NBIN) hist[i] = 0;
}

__global__ __launch_bounds__(THREADS) void hist_k(
    const float* __restrict__ pxy, const float* __restrict__ pxz,
    const float* __restrict__ pyz, const float* __restrict__ pxt,
    const float* __restrict__ pyt, const float* __restrict__ pzt,
    int* __restrict__ hist, unsigned short* __restrict__ keys, int npts, int bpp)
{
    const int s = blockIdx.x / bpp;
    const int i = (blockIdx.x - s * bpp) * THREADS + threadIdx.x;
    if (i >= npts) return;
    const float2 pt = load_pt(s, i, pxy, pxz, pyz, pxt, pyt, pzt);
    const unsigned key = bin_key(pt);
    keys[(size_t)s * npts + i] = (unsigned short)key;
    atomicAdd(&hist[s * NBIN + key], 1);
}

// in-place: cursors overwrite hist. 1024 threads x 16 bins each.
__global__ __launch_bounds__(1024) void scan_k(int* __restrict__ hist)
{
    __shared__ int sb[1024];
    const int p = blockIdx.x;
    const int t = threadIdx.x;
    const int base = p * NBIN + t * 16;
    int h[16], pre[16];
    int run = 0;
    #pragma unroll
    for (int i = 0; i < 16; ++i) { h[i] = hist[base + i]; pre[i] = run; run += h[i]; }
    sb[t] = run;
    __syncthreads();
    for (int off = 1; off < 1024; off <<= 1) {
        const int v = (t >= off) ? sb[t - off] : 0;
        __syncthreads();
        sb[t] += v;
        __syncthreads();
    }
    const int start = sb[t] - run;   // exclusive within plane
    #pragma unroll
    for (int i = 0; i < 16; ++i) hist[base + i] = start + pre[i];
}

// 8 points per thread: 8 independent atomic->store chains in flight.
// writes sidx (sorted->orig, scattered) and inv (orig->sorted, coalesced).
__global__ __launch_bounds__(THREADS) void scatter_k(
    const unsigned short* __restrict__ keys, int* __restrict__ curs,
    int* __restrict__ sidx, int* __restrict__ inv, int npts, int bpb)
{
    const int s = blockIdx.x / bpb;
    const int base = (blockIdx.x - s * bpb) * (THREADS * SC_PPT) + threadIdx.x;
    const size_t sb = (size_t)s * npts;
    int idx[SC_PPT];
    unsigned key[SC_PPT];
    #pragma unroll
    for (int t = 0; t < SC_PPT; ++t) {
        idx[t] = base + t * THREADS;
        key[t] = keys[sb + idx[t]];
    }
    int pos[SC_PPT];
    #pragma unroll
    for (int t = 0; t < SC_PPT; ++t)
        pos[t] = atomicAdd(&curs[s * NBIN + key[t]], 1);
    #pragma unroll
    for (int t = 0; t < SC_PPT; ++t) {
        sidx[sb + pos[t]] = idx[t];
        inv[sb + idx[t]] = pos[t];
    }
}

// ---------------- sorted hash-grid gather -> bf16 enc rows (sorted order, 64B/row) ----------------
// Batched: 4 levels' 16 corner loads issued together for deep MLP.
__global__ __launch_bounds__(THREADS, 5) void gather_sorted_k(
    const float* __restrict__ pxy, const float* __restrict__ pxz,
    const float* __restrict__ pyz, const float* __restrict__ pxt,
    const float* __restrict__ pyt, const float* __restrict__ pzt,
    const float* __restrict__ tables, const int* __restrict__ sidx,
    unsigned* __restrict__ encP, int npts, int bpp)
{
    int bid = blockIdx.x;
    const int G = gridDim.x;
    if ((G & 7) == 0) {                       // XCD-aware chunked swizzle (bijective)
        const int chunk = G >> 3;
        bid = (bid & 7) * chunk + (bid >> 3);
    }
    const int s = bid / bpp;
    const int i = (bid - s * bpp) * THREADS + threadIdx.x;
    if (i >= npts) return;

    const int orig = sidx[(size_t)s * npts + i];
    const float2 pt = load_pt(s, orig, pxy, pxz, pyz, pxt, pyt, pzt);
    const float2* tab0 = ((const float2*)tables) + (size_t)s * LVLS * TSZ;

    unsigned ew[LVLS];
    #pragma unroll
    for (int g4 = 0; g4 < 4; ++g4) {
        float2 cor[16];
        float wxs[4], wys[4];
        #pragma unroll
        for (int q = 0; q < 4; ++q) {
            const int l = g4 * 4 + q;
            const float r = c_RES[l];
            const float fx = pt.x * r, fy = pt.y * r;
            const float flx = floorf(fx), fly = floorf(fy);
            wxs[q] = fx - flx; wys[q] = fy - fly;
            const unsigned x0 = (unsigned)(int)flx;
            const unsigned y0 = (unsigned)(int)fly;
            const unsigned hy0 = y0 * PRIME1;
            const unsigned hy1 = hy0 + PRIME1;
            const float2* tab = tab0 + (size_t)l * TSZ;
            cor[q * 4 + 0] = tab[(x0 ^ hy0) & TMASK];
            cor[q * 4 + 1] = tab[((x0 + 1u) ^ hy0) & TMASK];
            cor[q * 4 + 2] = tab[(x0 ^ hy1) & TMASK];
            cor[q * 4 + 3] = tab[((x0 + 1u) ^ hy1) & TMASK];
        }
        #pragma unroll
        for (int q = 0; q < 4; ++q) {
            const float wx = wxs[q], wy = wys[q];
            const float w00 = (1.f - wx) * (1.f - wy);
            const float w10 = wx * (1.f - wy);
            const float w01 = (1.f - wx) * wy;
            const float w11 = wx * wy;
            const float e0 = cor[q*4+0].x * w00 + cor[q*4+1].x * w10 + cor[q*4+2].x * w01 + cor[q*4+3].x * w11;
            const float e1 = cor[q*4+0].y * w00 + cor[q*4+1].y * w10 + cor[q*4+2].y * w01 + cor[q*4+3].y * w11;
            ew[g4 * 4 + q] = packbf2(e0, e1);
        }
    }

    // coalesced 64B row write at SORTED position
    uint4* dst = (uint4*)(encP + ((size_t)s * npts + i) * 16);
    dst[0] = make_uint4(ew[0],  ew[1],  ew[2],  ew[3]);
    dst[1] = make_uint4(ew[4],  ew[5],  ew[6],  ew[7]);
    dst[2] = make_uint4(ew[8],  ew[9],  ew[10], ew[11]);
    dst[3] = make_uint4(ew[12], ew[13], ew[14], ew[15]);
}

// ---------------- MFMA MLP: A gathered from per-plane sorted enc via inv ----------------
__global__ __launch_bounds__(256, 2) void mlp_mfma_k(
    const float* __restrict__ pxy, const float* __restrict__ pxz,
    const float* __restrict__ pyz, const float* __restrict__ pxt,
    const float* __restrict__ pyt, const float* __restrict__ pzt,
    const unsigned* __restrict__ encP, const int* __restrict__ inv,
    const unsigned short* __restrict__ W1Bg, const unsigned short* __restrict__ W2Bg,
    const float* __restrict__ W3, float* __restrict__ out, int npts)
{
    __shared__ uint4 sW1B[1792];          // 7 ksteps * 4 ntiles * 64 lanes * 16B
    __shared__ uint4 sW2B[512];
    __shared__ float sW3[192];
    __shared__ unsigned short sH1[4][1024];  // per-wave 16x64 bf16, XOR-swizzled

    const int tid = threadIdx.x;
    for (int i = tid; i < 1792; i += 256) sW1B[i] = ((const uint4*)W1Bg)[i];
    for (int i = tid; i < 512; i += 256) sW2B[i] = ((const uint4*)W2Bg)[i];
    for (int i = tid; i < 192; i += 256) sW3[i] = W3[i];
    __syncthreads();

    const int w = tid >> 6, lane = tid & 63;
    const int row = lane & 15, g = lane >> 4;
    const int blk0 = blockIdx.x * (64 * MLP_TILES);

    for (int it = 0; it < MLP_TILES; ++it) {
        const int p0 = blk0 + (it * 4 + w) * 16;
        if (p0 + 16 > npts) { __syncthreads(); __syncthreads(); continue; }

        const int p = p0 + row;
        // batch all A-fragment loads: 6 inv + 6 enc-gathers in flight together
        int ip[6];
        #pragma unroll
        for (int t = 0; t < 6; ++t) ip[t] = inv[(size_t)t * npts + p];
        uint4 av[6];
        #pragma unroll
        for (int t = 0; t < 6; ++t)
            av[t] = *(const uint4*)(encP + ((size_t)t * npts + ip[t]) * 16 + g * 4);

        // coord k-step fragment (k=192..207 valid; B zero-padded beyond 204)
        unsigned cw0 = 0, cw1 = 0, cw2 = 0, cw3 = 0;
        if (g == 0) {
            float2 c0 = load_pt(0, p, pxy, pxz, pyz, pxt, pyt, pzt);
            float2 c1 = load_pt(1, p, pxy, pxz, pyz, pxt, pyt, pzt);
            float2 c2 = load_pt(2, p, pxy, pxz, pyz, pxt, pyt, pzt);
            float2 c3 = load_pt(3, p, pxy, pxz, pyz, pxt, pyt, pzt);
            cw0 = packbf2(c0.x, c0.y); cw1 = packbf2(c1.x, c1.y);
            cw2 = packbf2(c2.x, c2.y); cw3 = packbf2(c3.x, c3.y);
        } else if (g == 1) {
            float2 c4 = load_pt(4, p, pxy, pxz, pyz, pxt, pyt, pzt);
            float2 c5 = load_pt(5, p, pxy, pxz, pyz, pxt, pyt, pzt);
            cw0 = packbf2(c4.x, c4.y); cw1 = packbf2(c5.x, c5.y);
        }
        const uint4 avc = make_uint4(cw0, cw1, cw2, cw3);

        f32x4 acc0 = {0.f,0.f,0.f,0.f}, acc1 = acc0, acc2_ = acc0, acc3 = acc0;
        #pragma unroll
        for (int t = 0; t < 6; ++t) {
            const bf16x8 a = *(const bf16x8*)&av[t];
            acc0 = __builtin_amdgcn_mfma_f32_16x16x32_bf16(a, *(const bf16x8*)&sW1B[(t*4+0)*64 + lane], acc0, 0, 0, 0);
            acc1 = __builtin_amdgcn_mfma_f32_16x16x32_bf16(a, *(const bf16x8*)&sW1B[(t*4+1)*64 + lane], acc1, 0, 0, 0);
            acc2_ = __builtin_amdgcn_mfma_f32_16x16x32_bf16(a, *(const bf16x8*)&sW1B[(t*4+2)*64 + lane], acc2_, 0, 0, 0);
            acc3 = __builtin_amdgcn_mfma_f32_16x16x32_bf16(a, *(const bf16x8*)&sW1B[(t*4+3)*64 + lane], acc3, 0, 0, 0);
        }
        {
            const bf16x8 a = *(const bf16x8*)&avc;
            acc0 = __builtin_amdgcn_mfma_f32_16x16x32_bf16(a, *(const bf16x8*)&sW1B[(6*4+0)*64 + lane], acc0, 0, 0, 0);
            acc1 = __builtin_amdgcn_mfma_f32_16x16x32_bf16(a, *(const bf16x8*)&sW1B[(6*4+1)*64 + lane], acc1, 0, 0, 0);
            acc2_ = __builtin_amdgcn_mfma_f32_16x16x32_bf16(a, *(const bf16x8*)&sW1B[(6*4+2)*64 + lane], acc2_, 0, 0, 0);
            acc3 = __builtin_amdgcn_mfma_f32_16x16x32_bf16(a, *(const bf16x8*)&sW1B[(6*4+3)*64 + lane], acc3, 0, 0, 0);
        }

        // D layout: col = lane&15, row(point) = g*4 + reg
        #pragma unroll
        for (int r = 0; r < 4; ++r) {
            const int rr = g * 4 + r;
            const int base = rr * 64;
            const int swz = (rr & 7) << 3;
            sH1[w][(base + 0 * 16 + row) ^ swz] = bf16rne(fmaxf(acc0[r], 0.f));
            sH1[w][(base + 1 * 16 + row) ^ swz] = bf16rne(fmaxf(acc1[r], 0.f));
            sH1[w][(base + 2 * 16 + row) ^ swz] = bf16rne(fmaxf(acc2_[r], 0.f));
            sH1[w][(base + 3 * 16 + row) ^ swz] = bf16rne(fmaxf(acc3[r], 0.f));
        }
        __syncthreads();

        f32x4 b0 = {0.f,0.f,0.f,0.f}, b1 = b0, b2 = b0, b3 = b0;
        #pragma unroll
        for (int t = 0; t < 2; ++t) {
            const int kidx = (row * 64 + t * 32 + g * 8) ^ ((row & 7) << 3);
            const bf16x8 a2 = *(const bf16x8*)&sH1[w][kidx];
            b0 = __builtin_amdgcn_mfma_f32_16x16x32_bf16(a2, *(const bf16x8*)&sW2B[(t*4+0)*64 + lane], b0, 0, 0, 0);
            b1 = __builtin_amdgcn_mfma_f32_16x16x32_bf16(a2, *(const bf16x8*)&sW2B[(t*4+1)*64 + lane], b1, 0, 0, 0);
            b2 = __builtin_amdgcn_mfma_f32_16x16x32_bf16(a2, *(const bf16x8*)&sW2B[(t*4+2)*64 + lane], b2, 0, 0, 0);
            b3 = __builtin_amdgcn_mfma_f32_16x16x32_bf16(a2, *(const bf16x8*)&sW2B[(t*4+3)*64 + lane], b3, 0, 0, 0);
        }

        float o[4][3];
        #pragma unroll
        for (int r = 0; r < 4; ++r) { o[r][0] = 0.f; o[r][1] = 0.f; o[r][2] = 0.f; }
        #pragma unroll
        for (int n = 0; n < 4; ++n) {
            const int m = n * 16 + row;
            const float w30 = sW3[m * 3 + 0], w31 = sW3[m * 3 + 1], w32 = sW3[m * 3 + 2];
            const f32x4 bb = (n == 0) ? b0 : (n == 1) ? b1 : (n == 2) ? b2 : b3;
            #pragma unroll
            for (int r = 0; r < 4; ++r) {
                const float h = fmaxf(bb[r], 0.f);
                o[r][0] += h * w30; o[r][1] += h * w31; o[r][2] += h * w32;
            }
        }
        #pragma unroll
        for (int m = 1; m < 16; m <<= 1) {
            #pragma unroll
            for (int r = 0; r < 4; ++r) {
                o[r][0] += __shfl_xor(o[r][0], m, 64);
                o[r][1] += __shfl_xor(o[r][1], m, 64);
                o[r][2] += __shfl_xor(o[r][2], m, 64);
            }
        }
        if (row == 0) {
            #pragma unroll
            for (int r = 0; r < 4; ++r) {
                const int pp = p0 + g * 4 + r;
                out[pp * 3 + 0] = o[r][0];
                out[pp * 3 + 1] = o[r][1];
                out[pp * 3 + 2] = o[r][2];
            }
        }
        __syncthreads();   // WAR: reads done before next iter overwrites sH1
    }
}

// ---------------- Fallback: fused fp32 kernel (used only if ws too small) ----------------
__global__ __launch_bounds__(THREADS, 4) void fused_mono(
    const float* __restrict__ pxy, const float* __restrict__ pxz,
    const float* __restrict__ pyz, const float* __restrict__ pxt,
    const float* __restrict__ pyt, const float* __restrict__ pzt,
    const float* __restrict__ tables, const float* __restrict__ W1,
    const float* __restrict__ W2, const float* __restrict__ W3,
    float* __restrict__ out, int npts)
{
    const int gid = blockIdx.x * THREADS + threadIdx.x;

    float h1[HID];
    #pragma unroll
    for (int k = 0; k < HID; ++k) h1[k] = 0.f;

    #pragma unroll 1
    for (int s = 0; s < 6; ++s) {
        const float2 pt = load_pt(s, gid, pxy, pxz, pyz, pxt, pyt, pzt);
        const float px = pt.x, py = pt.y;
        const float2* tbase = ((const float2*)tables) + (size_t)s * LVLS * TSZ;
        const float* w1s = W1 + (s * 34) * HID;

        #pragma unroll 2
        for (int l = 0; l < LVLS; ++l) {
            const float r = c_RES[l];
            const float fx = px * r, fy = py * r;
            const float flx = floorf(fx), fly = floorf(fy);
            const float wx = fx - flx, wy = fy - fly;
            const unsigned x0 = (unsigned)(int)flx;
            const unsigned y0 = (unsigned)(int)fly;
            const unsigned hy0 = y0 * PRIME1;
            const unsigned hy1 = hy0 + PRIME1;
            const float2* tab = tbase + (size_t)l * TSZ;
            const float2 f00 = tab[(x0 ^ hy0) & TMASK];
            const float2 f10 = tab[((x0 + 1u) ^ hy0) & TMASK];
            const float2 f01 = tab[(x0 ^ hy1) & TMASK];
            const float2 f11 = tab[((x0 + 1u) ^ hy1) & TMASK];
            const float w00 = (1.f - wx) * (1.f - wy);
            const float w10 = wx * (1.f - wy);
            const float w01 = (1.f - wx) * wy;
            const float w11 = wx * wy;
            const float e0 = f00.x * w00 + f10.x * w10 + f01.x * w01 + f11.x * w11;
            const float e1 = f00.y * w00 + f10.y * w10 + f01.y * w01 + f11.y * w11;
            const float4* wa = (const float4*)(w1s + (2 * l) * HID);
            const float4* wb = wa + 16;
            #pragma unroll
            for (int q = 0; q < 16; ++q) {
                const float4 a = wa[q];
                const float4 b = wb[q];
                h1[4*q+0] += e0 * a.x + e1 * b.x;
                h1[4*q+1] += e0 * a.y + e1 * b.y;
                h1[4*q+2] += e0 * a.z + e1 * b.z;
                h1[4*q+3] += e0 * a.w + e1 * b.w;
            }
        }
        const float4* wa = (const float4*)(w1s + 32 * HID);
        const float4* wb = wa + 16;
        #pragma unroll
        for (int q = 0; q < 16; ++q) {
            const float4 a = wa[q];
            const float4 b = wb[q];
            h1[4*q+0] += px * a.x + py * b.x;
            h1[4*q+1] += px * a.y + py * b.y;
            h1[4*q+2] += px * a.z + py * b.z;
            h1[4*q+3] += px * a.w + py * b.w;
        }
    }

    #pragma unroll
    for (int k = 0; k < HID; ++k) h1[k] = fmaxf(h1[k], 0.f);

    float o0 = 0.f, o1 = 0.f, o2 = 0.f;
    #pragma unroll 1
    for (int c = 0; c < 4; ++c) {
        float t[16];
        #pragma unroll
        for (int i = 0; i < 16; ++i) t[i] = 0.f;
        #pragma unroll
        for (int k = 0; k < HID; ++k) {
            const float4* w2r = (const float4*)(W2 + k * HID + c * 16);
            const float hk = h1[k];
            const float4 a = w2r[0];
            const float4 b = w2r[1];
            const float4 d = w2r[2];
            const float4 e = w2r[3];
            t[0]  += hk * a.x;  t[1]  += hk * a.y;  t[2]  += hk * a.z;  t[3]  += hk * a.w;
            t[4]  += hk * b.x;  t[5]  += hk * b.y;  t[6]  += hk * b.z;  t[7]  += hk * b.w;
            t[8]  += hk * d.x;  t[9]  += hk * d.y;  t[10] += hk * d.z;  t[11] += hk * d.w;
            t[12] += hk * e.x;  t[13] += hk * e.y;  t[14] += hk * e.z;  t[15] += hk * e.w;
        }
        #pragma unroll
        for (int i = 0; i < 16; ++i) {
            const float tt = fmaxf(t[i], 0.f);
            const int m = c * 16 + i;
            o0 += tt * W3[m * 3 + 0];
            o1 += tt * W3[m * 3 + 1];
            o2 += tt * W3[m * 3 + 2];
        }
    }

    if (gid < npts) {
        out[3 * gid + 0] = o0;
        out[3 * gid + 1] = o1;
        out[3 * gid + 2] = o2;
    }
}

extern "C" void kernel_launch(void* const* d_in, const int* in_sizes, int n_in,
                              void* d_out, int out_size, void* d_ws, size_t ws_size,
                              hipStream_t stream)
{
    const float* pxy = (const float*)d_in[0];
    const float* pxz = (const float*)d_in[1];
    const float* pyz = (const float*)d_in[2];
    const float* pxt = (const float*)d_in[3];
    const float* pyt = (const float*)d_in[4];
    const float* pzt = (const float*)d_in[5];
    const float* tables = (const float*)d_in[6];
    const float* W1 = (const float*)d_in[7];
    const float* W2 = (const float*)d_in[8];
    const float* W3 = (const float*)d_in[9];
    float* out = (float*)d_out;

    const int npts = in_sizes[0] / 2;
    const int bpp = (npts + THREADS - 1) / THREADS;

    // workspace layout: [W1B][W2B] [sidx 24MB][inv 24MB] [enc 384MB: 6 planes * npts * 64B]
    // transient keys (12MB) + hist (384KB) live INSIDE the enc region (consumed before gather).
    const size_t off_w1b  = 0;
    const size_t off_w2b  = 28672;
    const size_t off_sidx = 65536;
    const size_t off_inv  = off_sidx + (size_t)6 * npts * 4;
    size_t off_enc = off_inv + (size_t)6 * npts * 4;
    off_enc = (off_enc + 127) & ~(size_t)127;
    const size_t need = off_enc + (size_t)6 * npts * 64;

    if (ws_size >= need && (npts % (64 * MLP_TILES)) == 0 &&
        (npts % (THREADS * SC_PPT)) == 0) {
        char* ws = (char*)d_ws;
        unsigned short* W1B = (unsigned short*)(ws + off_w1b);
        unsigned short* W2B = (unsigned short*)(ws + off_w2b);
        int* sidx = (int*)(ws + off_sidx);
        int* inv  = (int*)(ws + off_inv);
        unsigned* encP = (unsigned*)(ws + off_enc);
        unsigned short* keys = (unsigned short*)encP;                       // 12 MB transient
        int* hist = (int*)((char*)encP + (size_t)6 * npts * 2);             // 384 KB transient

        hipLaunchKernelGGL(zero_hist_k, dim3((6 * NBIN + THREADS - 1) / THREADS),
                           dim3(THREADS), 0, stream, hist);
        hipLaunchKernelGGL(hist_k, dim3(6 * bpp), dim3(THREADS), 0, stream,
                           pxy, pxz, pyz, pxt, pyt, pzt, hist, keys, npts, bpp);
        hipLaunchKernelGGL(scan_k, dim3(6), dim3(1024), 0, stream, hist);
        hipLaunchKernelGGL(pack_w1_k, dim3(56), dim3(256), 0, stream, W1, W1B);
        hipLaunchKernelGGL(pack_w2_k, dim3(16), dim3(256), 0, stream, W2, W2B);
        const int bpb = npts / (THREADS * SC_PPT);
        hipLaunchKernelGGL(scatter_k, dim3(6 * bpb), dim3(THREADS), 0, stream,
                           keys, hist, sidx, inv, npts, bpb);
        hipLaunchKernelGGL(gather_sorted_k, dim3(6 * bpp), dim3(THREADS), 0, stream,
                           pxy, pxz, pyz, pxt, pyt, pzt, tables, sidx, encP, npts, bpp);
        hipLaunchKernelGGL(mlp_mfma_k, dim3(npts / (64 * MLP_TILES)), dim3(256), 0, stream,
                           pxy, pxz, pyz, pxt, pyt, pzt, encP, inv, W1B, W2B, W3, out, npts);
    } else {
        hipLaunchKernelGGL(fused_mono, dim3(bpp), dim3(THREADS), 0, stream,
                           pxy, pxz, pyz, pxt, pyt, pzt, tables, W1, W2, W3, out, npts);
    }
}